// Round 2
// baseline (2336.413 us; speedup 1.0000x reference)
//
#include <hip/hip_runtime.h>
#include <hip/hip_bf16.h>
#include <stdint.h>

// ---------------- problem constants ----------------
#define BATCH   2
#define SEQL    4096
#define DMODEL  1024
#define DIN     2048          // d_inner
#define NH      32
#define HDIM    64
#define DSTATE  128
#define CONVD   2304          // d_inner + 2*d_state
#define DPROJ   4384          // 2*d_inner + 2*d_state + nheads
#define NTOT    8192          // BATCH*SEQL
#define NBIG    6528          // padded: 4384 + 1024 + 1024 = 6432 -> 6528 (/128)
#define NREAL   6432
// Z (bf16) column layout: [0,2048)=z  [2048,4352)=xBC  [4352,4384)=dt
//   [4384,5408)=P (xn@Mzero)  [5408,6432)=Q (xn@Mone)
// After cumsum pass2: fp32 cumsum(Q) occupies bytes [0,4096) of each row
// (the dead z columns).

typedef __attribute__((ext_vector_type(8))) short short8;
typedef __attribute__((ext_vector_type(4))) float f32x4;

__device__ __forceinline__ unsigned short f2bf(float f) {
    unsigned int u = __builtin_bit_cast(unsigned int, f);
    return (unsigned short)((u + 0x7FFFu + ((u >> 16) & 1u)) >> 16);
}
__device__ __forceinline__ float bf2f(unsigned short u) {
    unsigned int v = ((unsigned int)u) << 16;
    return __builtin_bit_cast(float, v);
}

__device__ __forceinline__ void gload16(const void* g, void* l) {
    __builtin_amdgcn_global_load_lds(
        (const __attribute__((address_space(1))) unsigned int*)g,
        (__attribute__((address_space(3))) unsigned int*)l,
        16, 0, 0);
}

// ---------------- weight prep ----------------
// transpose fp32 [R,C] -> bf16 [C,R]
__global__ void transpose_cast_kernel(const float* __restrict__ in,
                                      unsigned short* __restrict__ out,
                                      int R, int C) {
    __shared__ float tile[32][33];
    int c0 = blockIdx.x * 32, r0 = blockIdx.y * 32;
    int tx = threadIdx.x, ty = threadIdx.y;
    #pragma unroll
    for (int i = ty; i < 32; i += 8)
        tile[i][tx] = in[(size_t)(r0 + i) * C + c0 + tx];
    __syncthreads();
    #pragma unroll
    for (int i = ty; i < 32; i += 8)
        out[(size_t)(c0 + i) * R + r0 + tx] = f2bf(tile[tx][i]);
}

__global__ void cast_bf16_kernel(const float* __restrict__ in,
                                 unsigned short* __restrict__ out, int n4) {
    int i = (blockIdx.x * 256 + threadIdx.x) * 4;
    if (i < n4) {
        float4 v = *(const float4*)(in + i);
        ushort4 o;
        o.x = f2bf(v.x); o.y = f2bf(v.y); o.z = f2bf(v.z); o.w = f2bf(v.w);
        *(ushort4*)(out + i) = o;
    }
}

__global__ void zero_pad_kernel(unsigned short* __restrict__ p, int n) {
    int i = blockIdx.x * 256 + threadIdx.x;
    if (i < n) p[i] = 0;
}

// ---------------- rmsnorm + cast ----------------
__global__ __launch_bounds__(256) void rmsnorm_cast_kernel(
    const float* __restrict__ x, const float* __restrict__ w,
    unsigned short* __restrict__ xn) {
    int tok = blockIdx.x, tid = threadIdx.x;
    float4 v = ((const float4*)(x + (size_t)tok * DMODEL))[tid];
    float ss = v.x*v.x + v.y*v.y + v.z*v.z + v.w*v.w;
    #pragma unroll
    for (int off = 32; off > 0; off >>= 1) ss += __shfl_xor(ss, off, 64);
    __shared__ float sred[4];
    if ((tid & 63) == 0) sred[tid >> 6] = ss;
    __syncthreads();
    float tot = sred[0] + sred[1] + sred[2] + sred[3];
    float r = rsqrtf(tot * (1.0f / DMODEL) + 1e-5f);
    float4 wv = ((const float4*)w)[tid];
    ushort4 o;
    o.x = f2bf(v.x * r * wv.x); o.y = f2bf(v.y * r * wv.y);
    o.z = f2bf(v.z * r * wv.z); o.w = f2bf(v.w * r * wv.w);
    ((ushort4*)(xn + (size_t)tok * DMODEL))[tid] = o;
}

// ---------------- GEMM: C[M,N] = A[M,K] @ B[N,K]^T  (bf16 in, fp32 acc) ----
// MODE 1: bf16 out.  MODE 2: fp32 out = acc + x + P(bf16) + Qc(fp32 in z-region).
template<int MODE>
__global__ __launch_bounds__(256) void gemm_bt_kernel(
    const unsigned short* __restrict__ A, int lda,
    const unsigned short* __restrict__ B, int ldb,
    void* __restrict__ Cout, int ldc, int K,
    const float* __restrict__ addX, const unsigned short* __restrict__ Zbuf) {
    __shared__ __align__(16) unsigned short sA[128 * 64];
    __shared__ __align__(16) unsigned short sB[128 * 64];
    int tid = threadIdx.x;
    int bn = blockIdx.x, bm = blockIdx.y;
    int wave = tid >> 6, lane = tid & 63;
    int wm = wave >> 1, wn = wave & 1;
    f32x4 acc[4][4] = {};
    const unsigned short* Ab = A + (size_t)(bm * 128) * lda;
    const unsigned short* Bb = B + (size_t)(bn * 128) * ldb;
    int sRow = tid >> 3;            // 0..31
    int sCol = (tid & 7) * 8;       // 0..56
    for (int k0 = 0; k0 < K; k0 += 64) {
        __syncthreads();
        #pragma unroll
        for (int it = 0; it < 4; ++it) {
            int row = sRow + it * 32;
            gload16(&Ab[(size_t)row * lda + k0 + sCol], &sA[it * 2048 + tid * 8]);
            gload16(&Bb[(size_t)row * ldb + k0 + sCol], &sB[it * 2048 + tid * 8]);
        }
        __syncthreads();
        #pragma unroll
        for (int kk = 0; kk < 64; kk += 32) {
            short8 a[4], b[4];
            #pragma unroll
            for (int i = 0; i < 4; ++i) {
                int mr = wm * 64 + i * 16 + (lane & 15);
                a[i] = *(const short8*)&sA[mr * 64 + kk + (lane >> 4) * 8];
                int nr = wn * 64 + i * 16 + (lane & 15);
                b[i] = *(const short8*)&sB[nr * 64 + kk + (lane >> 4) * 8];
            }
            #pragma unroll
            for (int i = 0; i < 4; ++i)
                #pragma unroll
                for (int j = 0; j < 4; ++j)
                    acc[i][j] = __builtin_amdgcn_mfma_f32_16x16x32_bf16(
                        a[i], b[j], acc[i][j], 0, 0, 0);
        }
    }
    int rbase = bm * 128 + wm * 64 + ((lane >> 4) << 2);
    int cbase = bn * 128 + wn * 64 + (lane & 15);
    #pragma unroll
    for (int i = 0; i < 4; ++i) {
        #pragma unroll
        for (int r = 0; r < 4; ++r) {
            int gr = rbase + i * 16 + r;
            if constexpr (MODE == 1) {
                unsigned short* crow = (unsigned short*)Cout + (size_t)gr * ldc + cbase;
                #pragma unroll
                for (int j = 0; j < 4; ++j) crow[j * 16] = f2bf(acc[i][j][r]);
            } else {
                float* crow = (float*)Cout + (size_t)gr * ldc + cbase;
                const float* xr = addX + (size_t)gr * DMODEL + cbase;
                const unsigned short* zrow = Zbuf + (size_t)gr * NBIG;
                const float* qrow = (const float*)zrow;  // fp32 cumsum in z cols
                #pragma unroll
                for (int j = 0; j < 4; ++j)
                    crow[j * 16] = acc[i][j][r] + xr[j * 16]
                                 + bf2f(zrow[4384 + cbase + j * 16])
                                 + qrow[cbase + j * 16];
            }
        }
    }
}

// ---------------- conv4 (causal, depthwise) + silu ----------------
__global__ __launch_bounds__(256) void conv_silu_kernel(
    const unsigned short* __restrict__ Z, const float* __restrict__ convW,
    const float* __restrict__ convB, unsigned short* __restrict__ xbc) {
    int tok = blockIdx.x;
    int bi = tok >> 12, t = tok & 4095;
    for (int c = threadIdx.x; c < CONVD; c += 256) {
        float acc = convB[c];
        #pragma unroll
        for (int k = 0; k < 4; ++k) {
            int tt = t - 3 + k;
            if (tt >= 0)
                acc += bf2f(Z[(size_t)(bi * SEQL + tt) * NBIG + 2048 + c]) * convW[k * CONVD + c];
        }
        xbc[(size_t)tok * CONVD + c] = f2bf(acc / (1.0f + expf(-acc)));
    }
}

// ---------------- dt prep: softplus + dA ----------------
__global__ void dt_prep_kernel(const unsigned short* __restrict__ Z,
                               const float* __restrict__ dt_bias,
                               const float* __restrict__ A_log,
                               float* __restrict__ dts, float* __restrict__ dAo) {
    int i = blockIdx.x * 256 + threadIdx.x;
    if (i >= NTOT * NH) return;
    int tok = i >> 5, h = i & 31;
    float v = bf2f(Z[(size_t)tok * NBIG + 4352 + h]) + dt_bias[h];
    float sp = (v > 20.0f) ? v : log1pf(expf(v));
    float Ah = -expf(A_log[h]);
    dts[i] = sp;
    dAo[i] = expf(sp * Ah);
}

// ---------------- SSM sequential scan ----------------
// grid 512 = bi(2) x h(32) x pg(8); block 256 = 4 waves; wave owns 2 p-rows.
#define SCT 32
__global__ __launch_bounds__(256) void scan_kernel(
    const unsigned short* __restrict__ xbc, const float* __restrict__ dts,
    const float* __restrict__ dAg, unsigned short* __restrict__ y) {
    int blk = blockIdx.x;
    int pg = blk & 7;
    int h  = (blk >> 3) & 31;
    int bi = blk >> 8;
    int tid = threadIdx.x;
    int wave = tid >> 6, lane = tid & 63;
    __shared__ float sB[SCT][128];
    __shared__ float sC[SCT][128];
    __shared__ float sDtx[SCT][8];
    __shared__ float sDA[SCT];
    __shared__ float sY[SCT][8];
    float s00 = 0, s01 = 0, s10 = 0, s11 = 0;
    int tok0 = bi * SEQL;
    for (int c0 = 0; c0 < SEQL; c0 += SCT) {
        // stage B, C
        for (int idx = tid; idx < SCT * 128; idx += 256) {
            int st = idx >> 7, n = idx & 127;
            size_t base = (size_t)(tok0 + c0 + st) * CONVD;
            sB[st][n] = bf2f(xbc[base + 2048 + n]);
            sC[st][n] = bf2f(xbc[base + 2176 + n]);
        }
        // stage dt*x and dA
        if (tid < SCT * 8) {
            int st = tid >> 3, pl = tid & 7;
            int tok = tok0 + c0 + st;
            float d = dts[tok * NH + h];
            float xv = bf2f(xbc[(size_t)tok * CONVD + h * 64 + pg * 8 + pl]);
            sDtx[st][pl] = d * xv;
            if (pl == 0) sDA[st] = dAg[tok * NH + h];
        }
        __syncthreads();
        #pragma unroll 4
        for (int st = 0; st < SCT; ++st) {
            float b0 = sB[st][lane],      b1 = sB[st][lane + 64];
            float c0v = sC[st][lane],     c1v = sC[st][lane + 64];
            float da = sDA[st];
            float dtx0 = sDtx[st][wave * 2], dtx1 = sDtx[st][wave * 2 + 1];
            s00 = fmaf(s00, da, dtx0 * b0);
            s01 = fmaf(s01, da, dtx0 * b1);
            s10 = fmaf(s10, da, dtx1 * b0);
            s11 = fmaf(s11, da, dtx1 * b1);
            float p0 = fmaf(s01, c1v, s00 * c0v);
            float p1 = fmaf(s11, c1v, s10 * c0v);
            #pragma unroll
            for (int off = 32; off > 0; off >>= 1) {
                p0 += __shfl_xor(p0, off, 64);
                p1 += __shfl_xor(p1, off, 64);
            }
            if (lane == 0) { sY[st][wave * 2] = p0; sY[st][wave * 2 + 1] = p1; }
        }
        __syncthreads();
        if (tid < SCT * 8) {
            int st = tid >> 3, pl = tid & 7;
            y[(size_t)(tok0 + c0 + st) * DIN + h * 64 + pg * 8 + pl] =
                f2bf(sY[st][pl]);
        }
        __syncthreads();
    }
}

// ---------------- gated rmsnorm: mamba = rmsnorm((y + D*xs) * silu(z)) * gw --
// NOTE: y and mamba may alias (read phase fully precedes write phase per block).
__global__ __launch_bounds__(256) void gated_norm_kernel(
    const unsigned short* __restrict__ y, const unsigned short* __restrict__ xbc,
    const unsigned short* __restrict__ Z, const float* __restrict__ Dp,
    const float* __restrict__ gw, unsigned short* mamba) {
    int tok = blockIdx.x, tid = threadIdx.x;
    float vals[8];
    float ss = 0;
    #pragma unroll
    for (int i = 0; i < 8; ++i) {
        int c = tid + i * 256;
        float yv = bf2f(y[(size_t)tok * DIN + c]);
        float xv = bf2f(xbc[(size_t)tok * CONVD + c]);
        float zv = bf2f(Z[(size_t)tok * NBIG + c]);
        float g = (yv + Dp[c >> 6] * xv) * (zv / (1.0f + expf(-zv)));
        vals[i] = g;
        ss += g * g;
    }
    #pragma unroll
    for (int off = 32; off > 0; off >>= 1) ss += __shfl_xor(ss, off, 64);
    __shared__ float sred[4];
    if ((tid & 63) == 0) sred[tid >> 6] = ss;
    __syncthreads();
    float tot = sred[0] + sred[1] + sred[2] + sred[3];
    float r = rsqrtf(tot * (1.0f / DIN) + 1e-5f);
    #pragma unroll
    for (int i = 0; i < 8; ++i) {
        int c = tid + i * 256;
        mamba[(size_t)tok * DIN + c] = f2bf(vals[i] * r * gw[c]);
    }
}

// ---------------- chunked cumsum over L of Q (bf16 col [5408,6432)) --------
// pass2 writes fp32 running sum into the dead z-column bytes [0,4096) of row.
__global__ void cumsum_pass1_kernel(const unsigned short* __restrict__ Z,
                                    float* __restrict__ S) {
    int bi = blockIdx.x >> 5, ch = blockIdx.x & 31;
    #pragma unroll
    for (int j = 0; j < 4; ++j) {
        int c = threadIdx.x + j * 256;
        size_t base = (size_t)(bi * SEQL + ch * 128) * NBIG;
        float s = 0;
        for (int t = 0; t < 128; ++t)
            s += bf2f(Z[base + (size_t)t * NBIG + 5408 + c]);
        S[(bi * 32 + ch) * 1024 + c] = s;
    }
}

__global__ void cumsum_pass2_kernel(unsigned short* __restrict__ Z,
                                    const float* __restrict__ S) {
    int bi = blockIdx.x >> 5, ch = blockIdx.x & 31;
    #pragma unroll
    for (int j = 0; j < 4; ++j) {
        int c = threadIdx.x + j * 256;
        float run = 0;
        for (int k = 0; k < ch; ++k) run += S[(bi * 32 + k) * 1024 + c];
        size_t base = (size_t)(bi * SEQL + ch * 128) * NBIG;
        for (int t = 0; t < 128; ++t) {
            size_t row = base + (size_t)t * NBIG;
            run += bf2f(Z[row + 5408 + c]);
            ((float*)(Z + row))[c] = run;
        }
    }
}

// ---------------- launch ----------------
extern "C" void kernel_launch(void* const* d_in, const int* in_sizes, int n_in,
                              void* d_out, int out_size, void* d_ws, size_t ws_size,
                              hipStream_t stream) {
    (void)in_sizes; (void)n_in; (void)out_size; (void)ws_size;
    const float* x        = (const float*)d_in[0];
    const float* norm_w   = (const float*)d_in[1];
    const float* in_projW = (const float*)d_in[2];
    const float* conv_W   = (const float*)d_in[3];
    const float* conv_b   = (const float*)d_in[4];
    const float* dt_bias  = (const float*)d_in[5];
    const float* A_log    = (const float*)d_in[6];
    const float* Dp       = (const float*)d_in[7];
    const float* gnorm_w  = (const float*)d_in[8];
    const float* zero_W   = (const float*)d_in[9];
    const float* one_W    = (const float*)d_in[10];
    const float* fusion_W = (const float*)d_in[11];
    float* out = (float*)d_out;

    char* p = (char*)d_ws;
    auto alloc = [&](size_t bytes) { char* r = p; p += (bytes + 255) & ~(size_t)255; return r; };
    // persistent
    unsigned short* Wf_t  = (unsigned short*)alloc((size_t)DMODEL * 6144 * 2);  // 12.6 MB
    // prep pool (dead after main GEMM) -> reused as xbc
    char* pool0 = p;
    unsigned short* xn_bf = (unsigned short*)alloc((size_t)NTOT * DMODEL * 2);  // 16.8 MB
    unsigned short* zWb   = (unsigned short*)alloc((size_t)DMODEL * DIN * 2);   //  4.2 MB
    unsigned short* oWb   = (unsigned short*)alloc((size_t)DMODEL * DIN * 2);   //  4.2 MB
    unsigned short* Bt    = (unsigned short*)alloc((size_t)NBIG * DMODEL * 2);  // 13.4 MB
    unsigned short* xbc   = (unsigned short*)pool0;  // alias, 37.7 MB needed <= 38.5 pool
    // small fp32
    float* dts  = (float*)alloc((size_t)NTOT * NH * 4);
    float* dAb  = (float*)alloc((size_t)NTOT * NH * 4);
    float* Sb   = (float*)alloc((size_t)2 * 32 * 1024 * 4);
    // y and mamba share one bf16 buffer (gated_norm reads then writes)
    unsigned short* ym = (unsigned short*)alloc((size_t)NTOT * DIN * 2);        // 33.6 MB
    // Z
    unsigned short* Zbf = (unsigned short*)alloc((size_t)NTOT * NBIG * 2);      // 107 MB
    // total ~194 MB

    // weight prep
    transpose_cast_kernel<<<dim3(DPROJ / 32, DMODEL / 32), dim3(32, 8), 0, stream>>>(
        in_projW, Bt, DMODEL, DPROJ);
    transpose_cast_kernel<<<dim3(DMODEL / 32, 6144 / 32), dim3(32, 8), 0, stream>>>(
        fusion_W, Wf_t, 6144, DMODEL);
    cast_bf16_kernel<<<2048, 256, 0, stream>>>(zero_W, zWb, DMODEL * DIN);
    cast_bf16_kernel<<<2048, 256, 0, stream>>>(one_W, oWb, DMODEL * DIN);
    zero_pad_kernel<<<384, 256, 0, stream>>>(
        Bt + (size_t)NREAL * DMODEL, (NBIG - NREAL) * DMODEL);

    // xn = rmsnorm(x) in bf16
    rmsnorm_cast_kernel<<<NTOT, 256, 0, stream>>>(x, norm_w, xn_bf);

    // Mzero^T, Mone^T into Bt rows [4384,6432)  (bf16 out)
    gemm_bt_kernel<1><<<dim3(8, 8), 256, 0, stream>>>(
        Wf_t + 2048, 6144, zWb, DIN, Bt + (size_t)4384 * DMODEL, DMODEL, DIN,
        nullptr, nullptr);
    gemm_bt_kernel<1><<<dim3(8, 8), 256, 0, stream>>>(
        Wf_t + 4096, 6144, oWb, DIN, Bt + (size_t)5408 * DMODEL, DMODEL, DIN,
        nullptr, nullptr);

    // main GEMM: Z = xn @ [in_proj | Mzero | Mone]  (bf16 out)
    gemm_bt_kernel<1><<<dim3(NBIG / 128, NTOT / 128), 256, 0, stream>>>(
        xn_bf, DMODEL, Bt, DMODEL, Zbf, NBIG, DMODEL, nullptr, nullptr);

    conv_silu_kernel<<<NTOT, 256, 0, stream>>>(Zbf, conv_W, conv_b, xbc);
    dt_prep_kernel<<<(NTOT * NH) / 256, 256, 0, stream>>>(Zbf, dt_bias, A_log, dts, dAb);
    scan_kernel<<<512, 256, 0, stream>>>(xbc, dts, dAb, ym);
    gated_norm_kernel<<<NTOT, 256, 0, stream>>>(ym, xbc, Zbf, Dp, gnorm_w, ym);

    cumsum_pass1_kernel<<<64, 256, 0, stream>>>(Zbf, Sb);
    cumsum_pass2_kernel<<<64, 256, 0, stream>>>(Zbf, Sb);

    // out = x + mamba @ W0 + P + Qc
    gemm_bt_kernel<2><<<dim3(DMODEL / 128, NTOT / 128), 256, 0, stream>>>(
        ym, DIN, Wf_t, 6144, out, DMODEL, DIN, x, Zbf);
}

// Round 3
// 933.392 us; speedup vs baseline: 2.5031x; 2.5031x over previous
//
#include <hip/hip_runtime.h>
#include <hip/hip_bf16.h>
#include <stdint.h>

// ---------------- problem constants ----------------
#define BATCH   2
#define SEQL    4096
#define DMODEL  1024
#define DIN     2048          // d_inner
#define NH      32
#define HDIM    64
#define DSTATE  128
#define CONVD   2304          // d_inner + 2*d_state
#define DPROJ   4384          // 2*d_inner + 2*d_state + nheads
#define NTOT    8192          // BATCH*SEQL
#define NBIG    6528          // padded: 4384 + 1024 + 1024 = 6432 -> 6528 (/128)
#define NREAL   6432
#define CHT     128           // SSD chunk length
#define NCH     32            // chunks per batch-sequence (4096/128)
// Z (bf16) column layout: [0,2048)=z  [2048,4352)=xBC  [4352,4384)=dt
//   [4384,5408)=P (xn@Mzero)  [5408,6432)=Q (xn@Mone)
// After cumsum pass2: fp32 cumsum(Q) occupies bytes [0,4096) of each row.

typedef __attribute__((ext_vector_type(8))) short short8;
typedef __attribute__((ext_vector_type(4))) float f32x4;

__device__ __forceinline__ unsigned short f2bf(float f) {
    unsigned int u = __builtin_bit_cast(unsigned int, f);
    return (unsigned short)((u + 0x7FFFu + ((u >> 16) & 1u)) >> 16);
}
__device__ __forceinline__ float bf2f(unsigned short u) {
    unsigned int v = ((unsigned int)u) << 16;
    return __builtin_bit_cast(float, v);
}

__device__ __forceinline__ void gload16(const void* g, void* l) {
    __builtin_amdgcn_global_load_lds(
        (const __attribute__((address_space(1))) unsigned int*)g,
        (__attribute__((address_space(3))) unsigned int*)l,
        16, 0, 0);
}

// ---------------- weight prep ----------------
__global__ void transpose_cast_kernel(const float* __restrict__ in,
                                      unsigned short* __restrict__ out,
                                      int R, int C) {
    __shared__ float tile[32][33];
    int c0 = blockIdx.x * 32, r0 = blockIdx.y * 32;
    int tx = threadIdx.x, ty = threadIdx.y;
    #pragma unroll
    for (int i = ty; i < 32; i += 8)
        tile[i][tx] = in[(size_t)(r0 + i) * C + c0 + tx];
    __syncthreads();
    #pragma unroll
    for (int i = ty; i < 32; i += 8)
        out[(size_t)(c0 + i) * R + r0 + tx] = f2bf(tile[tx][i]);
}

__global__ void cast_bf16_kernel(const float* __restrict__ in,
                                 unsigned short* __restrict__ out, int n4) {
    int i = (blockIdx.x * 256 + threadIdx.x) * 4;
    if (i < n4) {
        float4 v = *(const float4*)(in + i);
        ushort4 o;
        o.x = f2bf(v.x); o.y = f2bf(v.y); o.z = f2bf(v.z); o.w = f2bf(v.w);
        *(ushort4*)(out + i) = o;
    }
}

__global__ void zero_pad_kernel(unsigned short* __restrict__ p, int n) {
    int i = blockIdx.x * 256 + threadIdx.x;
    if (i < n) p[i] = 0;
}

// ---------------- rmsnorm + cast ----------------
__global__ __launch_bounds__(256) void rmsnorm_cast_kernel(
    const float* __restrict__ x, const float* __restrict__ w,
    unsigned short* __restrict__ xn) {
    int tok = blockIdx.x, tid = threadIdx.x;
    float4 v = ((const float4*)(x + (size_t)tok * DMODEL))[tid];
    float ss = v.x*v.x + v.y*v.y + v.z*v.z + v.w*v.w;
    #pragma unroll
    for (int off = 32; off > 0; off >>= 1) ss += __shfl_xor(ss, off, 64);
    __shared__ float sred[4];
    if ((tid & 63) == 0) sred[tid >> 6] = ss;
    __syncthreads();
    float tot = sred[0] + sred[1] + sred[2] + sred[3];
    float r = rsqrtf(tot * (1.0f / DMODEL) + 1e-5f);
    float4 wv = ((const float4*)w)[tid];
    ushort4 o;
    o.x = f2bf(v.x * r * wv.x); o.y = f2bf(v.y * r * wv.y);
    o.z = f2bf(v.z * r * wv.z); o.w = f2bf(v.w * r * wv.w);
    ((ushort4*)(xn + (size_t)tok * DMODEL))[tid] = o;
}

// ---------------- GEMM: C[M,N] = A[M,K] @ B[N,K]^T  (bf16 in, fp32 acc) ----
template<int MODE>
__global__ __launch_bounds__(256) void gemm_bt_kernel(
    const unsigned short* __restrict__ A, int lda,
    const unsigned short* __restrict__ B, int ldb,
    void* __restrict__ Cout, int ldc, int K,
    const float* __restrict__ addX, const unsigned short* __restrict__ Zbuf) {
    __shared__ __align__(16) unsigned short sA[128 * 64];
    __shared__ __align__(16) unsigned short sB[128 * 64];
    int tid = threadIdx.x;
    int bn = blockIdx.x, bm = blockIdx.y;
    int wave = tid >> 6, lane = tid & 63;
    int wm = wave >> 1, wn = wave & 1;
    f32x4 acc[4][4] = {};
    const unsigned short* Ab = A + (size_t)(bm * 128) * lda;
    const unsigned short* Bb = B + (size_t)(bn * 128) * ldb;
    int sRow = tid >> 3;
    int sCol = (tid & 7) * 8;
    for (int k0 = 0; k0 < K; k0 += 64) {
        __syncthreads();
        #pragma unroll
        for (int it = 0; it < 4; ++it) {
            int row = sRow + it * 32;
            gload16(&Ab[(size_t)row * lda + k0 + sCol], &sA[it * 2048 + tid * 8]);
            gload16(&Bb[(size_t)row * ldb + k0 + sCol], &sB[it * 2048 + tid * 8]);
        }
        __syncthreads();
        #pragma unroll
        for (int kk = 0; kk < 64; kk += 32) {
            short8 a[4], b[4];
            #pragma unroll
            for (int i = 0; i < 4; ++i) {
                int mr = wm * 64 + i * 16 + (lane & 15);
                a[i] = *(const short8*)&sA[mr * 64 + kk + (lane >> 4) * 8];
                int nr = wn * 64 + i * 16 + (lane & 15);
                b[i] = *(const short8*)&sB[nr * 64 + kk + (lane >> 4) * 8];
            }
            #pragma unroll
            for (int i = 0; i < 4; ++i)
                #pragma unroll
                for (int j = 0; j < 4; ++j)
                    acc[i][j] = __builtin_amdgcn_mfma_f32_16x16x32_bf16(
                        a[i], b[j], acc[i][j], 0, 0, 0);
        }
    }
    int rbase = bm * 128 + wm * 64 + ((lane >> 4) << 2);
    int cbase = bn * 128 + wn * 64 + (lane & 15);
    #pragma unroll
    for (int i = 0; i < 4; ++i) {
        #pragma unroll
        for (int r = 0; r < 4; ++r) {
            int gr = rbase + i * 16 + r;
            if constexpr (MODE == 1) {
                unsigned short* crow = (unsigned short*)Cout + (size_t)gr * ldc + cbase;
                #pragma unroll
                for (int j = 0; j < 4; ++j) crow[j * 16] = f2bf(acc[i][j][r]);
            } else {
                float* crow = (float*)Cout + (size_t)gr * ldc + cbase;
                const float* xr = addX + (size_t)gr * DMODEL + cbase;
                const unsigned short* zrow = Zbuf + (size_t)gr * NBIG;
                const float* qrow = (const float*)zrow;
                #pragma unroll
                for (int j = 0; j < 4; ++j)
                    crow[j * 16] = acc[i][j][r] + xr[j * 16]
                                 + bf2f(zrow[4384 + cbase + j * 16])
                                 + qrow[cbase + j * 16];
            }
        }
    }
}

// ---------------- conv4 (causal, depthwise) + silu ----------------
__global__ __launch_bounds__(256) void conv_silu_kernel(
    const unsigned short* __restrict__ Z, const float* __restrict__ convW,
    const float* __restrict__ convB, unsigned short* __restrict__ xbc) {
    int tok = blockIdx.x;
    int bi = tok >> 12, t = tok & 4095;
    for (int c = threadIdx.x; c < CONVD; c += 256) {
        float acc = convB[c];
        #pragma unroll
        for (int k = 0; k < 4; ++k) {
            int tt = t - 3 + k;
            if (tt >= 0)
                acc += bf2f(Z[(size_t)(bi * SEQL + tt) * NBIG + 2048 + c]) * convW[k * CONVD + c];
        }
        xbc[(size_t)tok * CONVD + c] = f2bf(acc / (1.0f + expf(-acc)));
    }
}

// ================= SSD chunked scan =================
// K1: per (bh, chunk): Y_intra via MFMA + chunk state summary T[p][n].
__global__ __launch_bounds__(256) void chunk_intra_kernel(
    const unsigned short* __restrict__ xbc, const unsigned short* __restrict__ Z,
    const float* __restrict__ dt_bias, const float* __restrict__ A_log,
    unsigned short* __restrict__ TS, float* __restrict__ abuf,
    unsigned short* __restrict__ ym) {
    __shared__ __align__(16) unsigned short B_lds[128 * 128];
    __shared__ __align__(16) unsigned short C_lds[128 * 128];
    __shared__ __align__(16) unsigned short BtM[128 * 128]; // Xtmp -> Bt -> M
    __shared__ __align__(16) unsigned short Xt[64 * 128];   // Xt[p][s]
    __shared__ float dt_lds[128], dtA_lds[128], cum_lds[128], w_lds[128];
    int tid = threadIdx.x;
    int kch = blockIdx.x, bh = blockIdx.y;
    int h = bh & 31, bi = bh >> 5;
    int tok0 = bi * SEQL + kch * CHT;
    // ---- stage: dt(softplus), B, C, X(into BtM temp) ----
    if (tid < 128) {
        int t = tid;
        float v = bf2f(Z[(size_t)(tok0 + t) * NBIG + 4352 + h]) + dt_bias[h];
        float sp = (v > 20.f) ? v : log1pf(expf(v));
        dt_lds[t] = sp;
        dtA_lds[t] = -sp * expf(A_log[h]);
    }
    for (int seg = tid; seg < 128 * 16; seg += 256) {
        int row = seg >> 4, c8 = seg & 15;
        size_t rb = (size_t)(tok0 + row) * CONVD;
        *(short8*)&B_lds[row * 128 + c8 * 8] = *(const short8*)&xbc[rb + 2048 + c8 * 8];
        *(short8*)&C_lds[row * 128 + c8 * 8] = *(const short8*)&xbc[rb + 2176 + c8 * 8];
    }
    for (int seg = tid; seg < 128 * 8; seg += 256) {
        int srow = seg >> 3, c8 = seg & 7;
        *(short8*)&BtM[srow * 64 + c8 * 8] =
            *(const short8*)&xbc[(size_t)(tok0 + srow) * CONVD + h * 64 + c8 * 8];
    }
    __syncthreads();
    // ---- Xt[p][s] = X[s][p] ----
    for (int idx = tid; idx < 64 * 128; idx += 256) {
        int p = idx >> 7, s = idx & 127;
        Xt[p * 128 + s] = BtM[s * 64 + p];
    }
    __syncthreads();
    // ---- Bt into BtM; cum scan ----
    for (int idx = tid; idx < 128 * 128; idx += 256) {
        int n = idx >> 7, s = idx & 127;
        BtM[n * 128 + s] = B_lds[s * 128 + n];
    }
    if (tid < 128) {
        int lw = tid & 63;
        float v = dtA_lds[tid];
        #pragma unroll
        for (int off = 1; off < 64; off <<= 1) {
            float o = __shfl_up(v, off, 64);
            if (lw >= off) v += o;
        }
        cum_lds[tid] = v;
    }
    __syncthreads();
    if (tid >= 64 && tid < 128) cum_lds[tid] += cum_lds[63];
    __syncthreads();
    if (tid < 128) {
        float cT = cum_lds[127];
        w_lds[tid] = __expf(cT - cum_lds[tid]) * dt_lds[tid];
        abuf[(size_t)(bh * NCH + kch) * 128 + tid] = __expf(cum_lds[tid]);
    }
    __syncthreads();
    int lane = tid & 63, wv = tid >> 6;
    int quad = lane >> 4, l15 = lane & 15;
    // ---- step4: T[p][n] = sum_s w_s x_s[p] B_s[n] ----
    {
        f32x4 acc[8] = {};
        for (int kk = 0; kk < 128; kk += 32) {
            int sbase = kk + quad * 8;
            short8 x8 = *(const short8*)&Xt[(16 * wv + l15) * 128 + sbase];
            short8 a;
            #pragma unroll
            for (int j = 0; j < 8; ++j)
                a[j] = (short)f2bf(bf2f((unsigned short)x8[j]) * w_lds[sbase + j]);
            #pragma unroll
            for (int jn = 0; jn < 8; ++jn) {
                short8 b = *(const short8*)&BtM[(16 * jn + l15) * 128 + sbase];
                acc[jn] = __builtin_amdgcn_mfma_f32_16x16x32_bf16(a, b, acc[jn], 0, 0, 0);
            }
        }
        size_t tsbase = (size_t)(bh * NCH + kch) * 8192;
        #pragma unroll
        for (int jn = 0; jn < 8; ++jn)
            #pragma unroll
            for (int r = 0; r < 4; ++r) {
                int p = 16 * wv + quad * 4 + r, n = 16 * jn + l15;
                TS[tsbase + p * 128 + n] = f2bf(acc[jn][r]);
            }
    }
    __syncthreads();  // Bt dead; M overwrites BtM
    // ---- step1: G = C @ B^T (wave owns t in [32wv, 32wv+32)) ----
    {
        f32x4 g[2][8] = {};
        for (int kk = 0; kk < 128; kk += 32) {
            short8 a0 = *(const short8*)&C_lds[(32 * wv + l15) * 128 + kk + quad * 8];
            short8 a1 = *(const short8*)&C_lds[(32 * wv + 16 + l15) * 128 + kk + quad * 8];
            #pragma unroll
            for (int js = 0; js < 8; ++js) {
                short8 b = *(const short8*)&B_lds[(16 * js + l15) * 128 + kk + quad * 8];
                g[0][js] = __builtin_amdgcn_mfma_f32_16x16x32_bf16(a0, b, g[0][js], 0, 0, 0);
                g[1][js] = __builtin_amdgcn_mfma_f32_16x16x32_bf16(a1, b, g[1][js], 0, 0, 0);
            }
        }
        // ---- step2: M[t][s] = G * exp(cum_t - cum_s) * dt_s, causal ----
        #pragma unroll
        for (int it = 0; it < 2; ++it)
            #pragma unroll
            for (int js = 0; js < 8; ++js) {
                int s = 16 * js + l15;
                float cs = cum_lds[s], ds = dt_lds[s];
                #pragma unroll
                for (int r = 0; r < 4; ++r) {
                    int t = 32 * wv + 16 * it + quad * 4 + r;
                    float f = (s <= t) ? __expf(cum_lds[t] - cs) * ds : 0.f;
                    BtM[t * 128 + s] = f2bf(g[it][js][r] * f);
                }
            }
    }
    __syncthreads();
    // ---- step3: Y_intra = M @ Xt^T ----
    {
        f32x4 y[2][4] = {};
        for (int kk = 0; kk < 128; kk += 32) {
            short8 a0 = *(const short8*)&BtM[(32 * wv + l15) * 128 + kk + quad * 8];
            short8 a1 = *(const short8*)&BtM[(32 * wv + 16 + l15) * 128 + kk + quad * 8];
            #pragma unroll
            for (int jp = 0; jp < 4; ++jp) {
                short8 b = *(const short8*)&Xt[(16 * jp + l15) * 128 + kk + quad * 8];
                y[0][jp] = __builtin_amdgcn_mfma_f32_16x16x32_bf16(a0, b, y[0][jp], 0, 0, 0);
                y[1][jp] = __builtin_amdgcn_mfma_f32_16x16x32_bf16(a1, b, y[1][jp], 0, 0, 0);
            }
        }
        #pragma unroll
        for (int it = 0; it < 2; ++it)
            #pragma unroll
            for (int jp = 0; jp < 4; ++jp)
                #pragma unroll
                for (int r = 0; r < 4; ++r) {
                    int t = 32 * wv + 16 * it + quad * 4 + r;
                    int p = 16 * jp + l15;
                    ym[(size_t)(tok0 + t) * DIN + h * 64 + p] = f2bf(y[it][jp][r]);
                }
    }
}

// K2: state recurrence, in place on TS (read T_k, write S_before_k).
__global__ __launch_bounds__(128) void state_recur_kernel(
    unsigned short* __restrict__ TS, const float* __restrict__ abuf) {
    int bh = blockIdx.x >> 6, p = blockIdx.x & 63, n = threadIdx.x;
    float s = 0.f;
    for (int k = 0; k < NCH; ++k) {
        size_t base = ((size_t)(bh * NCH + k) * 64 + p) * 128 + n;
        float aT = abuf[(size_t)(bh * NCH + k) * 128 + 127];
        float tv = bf2f(TS[base]);
        TS[base] = f2bf(s);
        s = fmaf(aT, s, tv);
    }
}

// K3: Y = Y_intra + (a .* C) @ S_prev^T + D*x
__global__ __launch_bounds__(256) void chunk_inter_kernel(
    const unsigned short* __restrict__ xbc, const unsigned short* __restrict__ TS,
    const float* __restrict__ abuf, const float* __restrict__ Dp,
    unsigned short* ym) {
    __shared__ __align__(16) unsigned short aC[128 * 128];
    __shared__ __align__(16) unsigned short S_lds[64 * 128];
    __shared__ float a_ld[128];
    int tid = threadIdx.x;
    int kch = blockIdx.x, bh = blockIdx.y;
    int h = bh & 31, bi = bh >> 5;
    int tok0 = bi * SEQL + kch * CHT;
    if (tid < 128) a_ld[tid] = abuf[(size_t)(bh * NCH + kch) * 128 + tid];
    __syncthreads();
    for (int seg = tid; seg < 128 * 16; seg += 256) {
        int t = seg >> 4, c8 = seg & 15;
        short8 v = *(const short8*)&xbc[(size_t)(tok0 + t) * CONVD + 2176 + c8 * 8];
        float at = a_ld[t];
        short8 o;
        #pragma unroll
        for (int j = 0; j < 8; ++j)
            o[j] = (short)f2bf(bf2f((unsigned short)v[j]) * at);
        *(short8*)&aC[t * 128 + c8 * 8] = o;
    }
    size_t tsbase = (size_t)(bh * NCH + kch) * 8192;
    for (int seg = tid; seg < 64 * 16; seg += 256) {
        int p = seg >> 4, c8 = seg & 15;
        *(short8*)&S_lds[p * 128 + c8 * 8] = *(const short8*)&TS[tsbase + p * 128 + c8 * 8];
    }
    __syncthreads();
    int lane = tid & 63, wv = tid >> 6;
    int quad = lane >> 4, l15 = lane & 15;
    f32x4 y[2][4] = {};
    for (int kk = 0; kk < 128; kk += 32) {
        short8 a0 = *(const short8*)&aC[(32 * wv + l15) * 128 + kk + quad * 8];
        short8 a1 = *(const short8*)&aC[(32 * wv + 16 + l15) * 128 + kk + quad * 8];
        #pragma unroll
        for (int jp = 0; jp < 4; ++jp) {
            short8 b = *(const short8*)&S_lds[(16 * jp + l15) * 128 + kk + quad * 8];
            y[0][jp] = __builtin_amdgcn_mfma_f32_16x16x32_bf16(a0, b, y[0][jp], 0, 0, 0);
            y[1][jp] = __builtin_amdgcn_mfma_f32_16x16x32_bf16(a1, b, y[1][jp], 0, 0, 0);
        }
    }
    float Dh = Dp[h];
    #pragma unroll
    for (int it = 0; it < 2; ++it)
        #pragma unroll
        for (int jp = 0; jp < 4; ++jp)
            #pragma unroll
            for (int r = 0; r < 4; ++r) {
                int t = 32 * wv + 16 * it + quad * 4 + r;
                int p = 16 * jp + l15;
                size_t yi = (size_t)(tok0 + t) * DIN + h * 64 + p;
                float xv = bf2f(xbc[(size_t)(tok0 + t) * CONVD + h * 64 + p]);
                float yv = y[it][jp][r] + bf2f(ym[yi]) + Dh * xv;
                ym[yi] = f2bf(yv);
            }
}

// ---------------- gated rmsnorm ----------------
__global__ __launch_bounds__(256) void gated_norm_kernel(
    const unsigned short* __restrict__ y, const unsigned short* __restrict__ xbc,
    const unsigned short* __restrict__ Z, const float* __restrict__ Dp,
    const float* __restrict__ gw, unsigned short* mamba) {
    int tok = blockIdx.x, tid = threadIdx.x;
    float vals[8];
    float ss = 0;
    #pragma unroll
    for (int i = 0; i < 8; ++i) {
        int c = tid + i * 256;
        float yv = bf2f(y[(size_t)tok * DIN + c]);
        float zv = bf2f(Z[(size_t)tok * NBIG + c]);
        float g = yv * (zv / (1.0f + expf(-zv)));
        vals[i] = g;
        ss += g * g;
    }
    #pragma unroll
    for (int off = 32; off > 0; off >>= 1) ss += __shfl_xor(ss, off, 64);
    __shared__ float sred[4];
    if ((tid & 63) == 0) sred[tid >> 6] = ss;
    __syncthreads();
    float tot = sred[0] + sred[1] + sred[2] + sred[3];
    float r = rsqrtf(tot * (1.0f / DIN) + 1e-5f);
    #pragma unroll
    for (int i = 0; i < 8; ++i) {
        int c = tid + i * 256;
        mamba[(size_t)tok * DIN + c] = f2bf(vals[i] * r * gw[c]);
    }
    (void)xbc; (void)Dp;
}

// ---------------- chunked cumsum over L of Q ----------------
__global__ void cumsum_pass1_kernel(const unsigned short* __restrict__ Z,
                                    float* __restrict__ S) {
    int bi = blockIdx.x >> 5, ch = blockIdx.x & 31;
    #pragma unroll
    for (int j = 0; j < 4; ++j) {
        int c = threadIdx.x + j * 256;
        size_t base = (size_t)(bi * SEQL + ch * 128) * NBIG;
        float s = 0;
        for (int t = 0; t < 128; ++t)
            s += bf2f(Z[base + (size_t)t * NBIG + 5408 + c]);
        S[(bi * 32 + ch) * 1024 + c] = s;
    }
}

__global__ void cumsum_pass2_kernel(unsigned short* __restrict__ Z,
                                    const float* __restrict__ S) {
    int bi = blockIdx.x >> 5, ch = blockIdx.x & 31;
    #pragma unroll
    for (int j = 0; j < 4; ++j) {
        int c = threadIdx.x + j * 256;
        float run = 0;
        for (int k = 0; k < ch; ++k) run += S[(bi * 32 + k) * 1024 + c];
        size_t base = (size_t)(bi * SEQL + ch * 128) * NBIG;
        for (int t = 0; t < 128; ++t) {
            size_t row = base + (size_t)t * NBIG;
            run += bf2f(Z[row + 5408 + c]);
            ((float*)(Z + row))[c] = run;
        }
    }
}

// ---------------- launch ----------------
extern "C" void kernel_launch(void* const* d_in, const int* in_sizes, int n_in,
                              void* d_out, int out_size, void* d_ws, size_t ws_size,
                              hipStream_t stream) {
    (void)in_sizes; (void)n_in; (void)out_size; (void)ws_size;
    const float* x        = (const float*)d_in[0];
    const float* norm_w   = (const float*)d_in[1];
    const float* in_projW = (const float*)d_in[2];
    const float* conv_W   = (const float*)d_in[3];
    const float* conv_b   = (const float*)d_in[4];
    const float* dt_bias  = (const float*)d_in[5];
    const float* A_log    = (const float*)d_in[6];
    const float* Dp       = (const float*)d_in[7];
    const float* gnorm_w  = (const float*)d_in[8];
    const float* zero_W   = (const float*)d_in[9];
    const float* one_W    = (const float*)d_in[10];
    const float* fusion_W = (const float*)d_in[11];
    float* out = (float*)d_out;

    char* p = (char*)d_ws;
    auto alloc = [&](size_t bytes) { char* r = p; p += (bytes + 255) & ~(size_t)255; return r; };
    unsigned short* Wf_t  = (unsigned short*)alloc((size_t)DMODEL * 6144 * 2);
    char* pool0 = p;
    unsigned short* xn_bf = (unsigned short*)alloc((size_t)NTOT * DMODEL * 2);
    unsigned short* zWb   = (unsigned short*)alloc((size_t)DMODEL * DIN * 2);
    unsigned short* oWb   = (unsigned short*)alloc((size_t)DMODEL * DIN * 2);
    unsigned short* Bt    = (unsigned short*)alloc((size_t)NBIG * DMODEL * 2);
    unsigned short* xbc   = (unsigned short*)pool0;  // alias over dead prep pool
    float* abuf = (float*)alloc((size_t)64 * NCH * 128 * 4);   // 1 MB
    float* Sb   = (float*)alloc((size_t)2 * 32 * 1024 * 4);
    unsigned short* ym  = (unsigned short*)alloc((size_t)NTOT * DIN * 2);
    unsigned short* Zbf = (unsigned short*)alloc((size_t)NTOT * NBIG * 2);
    // T/S chunk-state buffer lives in d_out (33,554,432 B, exact fit);
    // final GEMM overwrites it last.
    unsigned short* TS = (unsigned short*)d_out;

    // weight prep
    transpose_cast_kernel<<<dim3(DPROJ / 32, DMODEL / 32), dim3(32, 8), 0, stream>>>(
        in_projW, Bt, DMODEL, DPROJ);
    transpose_cast_kernel<<<dim3(DMODEL / 32, 6144 / 32), dim3(32, 8), 0, stream>>>(
        fusion_W, Wf_t, 6144, DMODEL);
    cast_bf16_kernel<<<2048, 256, 0, stream>>>(zero_W, zWb, DMODEL * DIN);
    cast_bf16_kernel<<<2048, 256, 0, stream>>>(one_W, oWb, DMODEL * DIN);
    zero_pad_kernel<<<384, 256, 0, stream>>>(
        Bt + (size_t)NREAL * DMODEL, (NBIG - NREAL) * DMODEL);

    rmsnorm_cast_kernel<<<NTOT, 256, 0, stream>>>(x, norm_w, xn_bf);

    gemm_bt_kernel<1><<<dim3(8, 8), 256, 0, stream>>>(
        Wf_t + 2048, 6144, zWb, DIN, Bt + (size_t)4384 * DMODEL, DMODEL, DIN,
        nullptr, nullptr);
    gemm_bt_kernel<1><<<dim3(8, 8), 256, 0, stream>>>(
        Wf_t + 4096, 6144, oWb, DIN, Bt + (size_t)5408 * DMODEL, DMODEL, DIN,
        nullptr, nullptr);

    gemm_bt_kernel<1><<<dim3(NBIG / 128, NTOT / 128), 256, 0, stream>>>(
        xn_bf, DMODEL, Bt, DMODEL, Zbf, NBIG, DMODEL, nullptr, nullptr);

    conv_silu_kernel<<<NTOT, 256, 0, stream>>>(Zbf, conv_W, conv_b, xbc);

    // SSD chunked scan
    chunk_intra_kernel<<<dim3(NCH, 64), 256, 0, stream>>>(
        xbc, Zbf, dt_bias, A_log, TS, abuf, ym);
    state_recur_kernel<<<64 * 64, 128, 0, stream>>>(TS, abuf);
    chunk_inter_kernel<<<dim3(NCH, 64), 256, 0, stream>>>(
        xbc, TS, abuf, Dp, ym);

    gated_norm_kernel<<<NTOT, 256, 0, stream>>>(ym, xbc, Zbf, Dp, gnorm_w, ym);

    cumsum_pass1_kernel<<<64, 256, 0, stream>>>(Zbf, Sb);
    cumsum_pass2_kernel<<<64, 256, 0, stream>>>(Zbf, Sb);

    gemm_bt_kernel<2><<<dim3(DMODEL / 128, NTOT / 128), 256, 0, stream>>>(
        ym, DIN, Wf_t, 6144, out, DMODEL, DIN, x, Zbf);
}

// Round 4
// 737.127 us; speedup vs baseline: 3.1696x; 1.2663x over previous
//
#include <hip/hip_runtime.h>
#include <hip/hip_bf16.h>
#include <stdint.h>

// ---------------- problem constants ----------------
#define BATCH   2
#define SEQL    4096
#define DMODEL  1024
#define DIN     2048          // d_inner
#define NH      32
#define HDIM    64
#define DSTATE  128
#define CONVD   2304          // d_inner + 2*d_state
#define DPROJ   4384          // 2*d_inner + 2*d_state + nheads
#define NTOT    8192          // BATCH*SEQL
#define NBIG    6528          // padded: 4384 + 1024 + 1024 = 6432 -> 6528 (/128)
#define NREAL   6432
#define CHT     128           // SSD chunk length
#define NCH     32            // chunks per batch-sequence (4096/128)
#define SP      136           // padded LDS row stride (halfwords): +8 keeps 16B align,
                              // rotates banks by 4/row -> structural-only conflicts
// Z (bf16) column layout: [0,2048)=z  [2048,4352)=xBC  [4352,4384)=dt
//   [4384,5408)=P (xn@Mzero)  [5408,6432)=Q (xn@Mone)
// After cumsum pass2: fp32 cumsum(Q) occupies bytes [0,4096) of each row.

typedef __attribute__((ext_vector_type(8))) short short8;
typedef __attribute__((ext_vector_type(4))) float f32x4;

__device__ __forceinline__ unsigned short f2bf(float f) {
    unsigned int u = __builtin_bit_cast(unsigned int, f);
    return (unsigned short)((u + 0x7FFFu + ((u >> 16) & 1u)) >> 16);
}
__device__ __forceinline__ float bf2f(unsigned short u) {
    unsigned int v = ((unsigned int)u) << 16;
    return __builtin_bit_cast(float, v);
}

__device__ __forceinline__ void gload16(const void* g, void* l) {
    __builtin_amdgcn_global_load_lds(
        (const __attribute__((address_space(1))) unsigned int*)g,
        (__attribute__((address_space(3))) unsigned int*)l,
        16, 0, 0);
}

// ---------------- weight prep ----------------
__global__ void transpose_cast_kernel(const float* __restrict__ in,
                                      unsigned short* __restrict__ out,
                                      int R, int C) {
    __shared__ float tile[32][33];
    int c0 = blockIdx.x * 32, r0 = blockIdx.y * 32;
    int tx = threadIdx.x, ty = threadIdx.y;
    #pragma unroll
    for (int i = ty; i < 32; i += 8)
        tile[i][tx] = in[(size_t)(r0 + i) * C + c0 + tx];
    __syncthreads();
    #pragma unroll
    for (int i = ty; i < 32; i += 8)
        out[(size_t)(c0 + i) * R + r0 + tx] = f2bf(tile[tx][i]);
}

__global__ void cast_bf16_kernel(const float* __restrict__ in,
                                 unsigned short* __restrict__ out, int n4) {
    int i = (blockIdx.x * 256 + threadIdx.x) * 4;
    if (i < n4) {
        float4 v = *(const float4*)(in + i);
        ushort4 o;
        o.x = f2bf(v.x); o.y = f2bf(v.y); o.z = f2bf(v.z); o.w = f2bf(v.w);
        *(ushort4*)(out + i) = o;
    }
}

__global__ void zero_pad_kernel(unsigned short* __restrict__ p, int n) {
    int i = blockIdx.x * 256 + threadIdx.x;
    if (i < n) p[i] = 0;
}

// ---------------- rmsnorm + cast ----------------
__global__ __launch_bounds__(256) void rmsnorm_cast_kernel(
    const float* __restrict__ x, const float* __restrict__ w,
    unsigned short* __restrict__ xn) {
    int tok = blockIdx.x, tid = threadIdx.x;
    float4 v = ((const float4*)(x + (size_t)tok * DMODEL))[tid];
    float ss = v.x*v.x + v.y*v.y + v.z*v.z + v.w*v.w;
    #pragma unroll
    for (int off = 32; off > 0; off >>= 1) ss += __shfl_xor(ss, off, 64);
    __shared__ float sred[4];
    if ((tid & 63) == 0) sred[tid >> 6] = ss;
    __syncthreads();
    float tot = sred[0] + sred[1] + sred[2] + sred[3];
    float r = rsqrtf(tot * (1.0f / DMODEL) + 1e-5f);
    float4 wv = ((const float4*)w)[tid];
    ushort4 o;
    o.x = f2bf(v.x * r * wv.x); o.y = f2bf(v.y * r * wv.y);
    o.z = f2bf(v.z * r * wv.z); o.w = f2bf(v.w * r * wv.w);
    ((ushort4*)(xn + (size_t)tok * DMODEL))[tid] = o;
}

// ---------------- GEMM: C[M,N] = A[M,K] @ B[N,K]^T  (bf16 in, fp32 acc) ----
template<int MODE>
__global__ __launch_bounds__(256) void gemm_bt_kernel(
    const unsigned short* __restrict__ A, int lda,
    const unsigned short* __restrict__ B, int ldb,
    void* __restrict__ Cout, int ldc, int K,
    const float* __restrict__ addX, const unsigned short* __restrict__ Zbuf) {
    __shared__ __align__(16) unsigned short sA[128 * 64];
    __shared__ __align__(16) unsigned short sB[128 * 64];
    int tid = threadIdx.x;
    int bn = blockIdx.x, bm = blockIdx.y;
    int wave = tid >> 6, lane = tid & 63;
    int wm = wave >> 1, wn = wave & 1;
    f32x4 acc[4][4] = {};
    const unsigned short* Ab = A + (size_t)(bm * 128) * lda;
    const unsigned short* Bb = B + (size_t)(bn * 128) * ldb;
    int sRow = tid >> 3;
    int sCol = (tid & 7) * 8;
    for (int k0 = 0; k0 < K; k0 += 64) {
        __syncthreads();
        #pragma unroll
        for (int it = 0; it < 4; ++it) {
            int row = sRow + it * 32;
            gload16(&Ab[(size_t)row * lda + k0 + sCol], &sA[it * 2048 + tid * 8]);
            gload16(&Bb[(size_t)row * ldb + k0 + sCol], &sB[it * 2048 + tid * 8]);
        }
        __syncthreads();
        #pragma unroll
        for (int kk = 0; kk < 64; kk += 32) {
            short8 a[4], b[4];
            #pragma unroll
            for (int i = 0; i < 4; ++i) {
                int mr = wm * 64 + i * 16 + (lane & 15);
                a[i] = *(const short8*)&sA[mr * 64 + kk + (lane >> 4) * 8];
                int nr = wn * 64 + i * 16 + (lane & 15);
                b[i] = *(const short8*)&sB[nr * 64 + kk + (lane >> 4) * 8];
            }
            #pragma unroll
            for (int i = 0; i < 4; ++i)
                #pragma unroll
                for (int j = 0; j < 4; ++j)
                    acc[i][j] = __builtin_amdgcn_mfma_f32_16x16x32_bf16(
                        a[i], b[j], acc[i][j], 0, 0, 0);
        }
    }
    int rbase = bm * 128 + wm * 64 + ((lane >> 4) << 2);
    int cbase = bn * 128 + wn * 64 + (lane & 15);
    #pragma unroll
    for (int i = 0; i < 4; ++i) {
        #pragma unroll
        for (int r = 0; r < 4; ++r) {
            int gr = rbase + i * 16 + r;
            if constexpr (MODE == 1) {
                unsigned short* crow = (unsigned short*)Cout + (size_t)gr * ldc + cbase;
                #pragma unroll
                for (int j = 0; j < 4; ++j) crow[j * 16] = f2bf(acc[i][j][r]);
            } else {
                float* crow = (float*)Cout + (size_t)gr * ldc + cbase;
                const float* xr = addX + (size_t)gr * DMODEL + cbase;
                const unsigned short* zrow = Zbuf + (size_t)gr * NBIG;
                const float* qrow = (const float*)zrow;
                #pragma unroll
                for (int j = 0; j < 4; ++j)
                    crow[j * 16] = acc[i][j][r] + xr[j * 16]
                                 + bf2f(zrow[4384 + cbase + j * 16])
                                 + qrow[cbase + j * 16];
            }
        }
    }
}

// ---------------- conv4 (causal, depthwise) + silu ----------------
__global__ __launch_bounds__(256) void conv_silu_kernel(
    const unsigned short* __restrict__ Z, const float* __restrict__ convW,
    const float* __restrict__ convB, unsigned short* __restrict__ xbc) {
    int tok = blockIdx.x;
    int bi = tok >> 12, t = tok & 4095;
    for (int c = threadIdx.x; c < CONVD; c += 256) {
        float acc = convB[c];
        #pragma unroll
        for (int k = 0; k < 4; ++k) {
            int tt = t - 3 + k;
            if (tt >= 0)
                acc += bf2f(Z[(size_t)(bi * SEQL + tt) * NBIG + 2048 + c]) * convW[k * CONVD + c];
        }
        xbc[(size_t)tok * CONVD + c] = f2bf(acc / (1.0f + expf(-acc)));
    }
}

// ================= SSD chunked scan =================
// K1: per (bh, chunk). LDS: Xt/Xw (64xSP) + BtM (128xSP, Bt then M) ~71KB
// -> 2 blocks/CU. C and B operands of G are read direct from global (layout
// already matches MFMA A/B fragment shape).
__global__ __launch_bounds__(256, 2) void chunk_intra_kernel(
    const unsigned short* __restrict__ xbc, const unsigned short* __restrict__ Z,
    const float* __restrict__ dt_bias, const float* __restrict__ A_log,
    unsigned short* __restrict__ TS, float* __restrict__ abuf,
    unsigned short* __restrict__ ym) {
    __shared__ __align__(16) unsigned short Xt[64 * SP];
    __shared__ __align__(16) unsigned short Xw[64 * SP];
    __shared__ __align__(16) unsigned short BtM[128 * SP];
    __shared__ float dt_lds[128], dtA_lds[128], cum_lds[128], w_lds[128];
    int tid = threadIdx.x;
    int kch = blockIdx.x, bh = blockIdx.y;
    int h = bh & 31, bi = bh >> 5;
    int tok0 = bi * SEQL + kch * CHT;
    const unsigned short* xb = xbc + (size_t)tok0 * CONVD;
    // ---- phase 0: dt/dtA + stage Bt[n][s], Xt[p][s] (s lane-major: 2-way writes)
    if (tid < 128) {
        float v = bf2f(Z[(size_t)(tok0 + tid) * NBIG + 4352 + h]) + dt_bias[h];
        float sp = (v > 20.f) ? v : log1pf(expf(v));
        dt_lds[tid] = sp;
        dtA_lds[tid] = -sp * expf(A_log[h]);
    }
    for (int seg = tid; seg < 128 * 16; seg += 256) {
        int s = seg & 127, nb = seg >> 7;
        short8 v = *(const short8*)&xb[(size_t)s * CONVD + 2048 + nb * 8];
        #pragma unroll
        for (int j = 0; j < 8; ++j) BtM[(nb * 8 + j) * SP + s] = (unsigned short)v[j];
    }
    for (int seg = tid; seg < 128 * 8; seg += 256) {
        int s = seg & 127, pb = seg >> 7;
        short8 v = *(const short8*)&xb[(size_t)s * CONVD + h * 64 + pb * 8];
        #pragma unroll
        for (int j = 0; j < 8; ++j) Xt[(pb * 8 + j) * SP + s] = (unsigned short)v[j];
    }
    __syncthreads();
    // ---- phase 1: inclusive scan of dtA -> cum; w = exp(cumT-cum)*dt
    if (tid < 128) {
        int lw = tid & 63;
        float v = dtA_lds[tid];
        #pragma unroll
        for (int off = 1; off < 64; off <<= 1) {
            float o = __shfl_up(v, off, 64);
            if (lw >= off) v += o;
        }
        cum_lds[tid] = v;
    }
    __syncthreads();
    if (tid >= 64 && tid < 128) cum_lds[tid] += cum_lds[63];
    __syncthreads();
    if (tid < 128) {
        float cT = cum_lds[127];
        w_lds[tid] = __expf(cT - cum_lds[tid]) * dt_lds[tid];
        abuf[(size_t)(bh * NCH + kch) * 128 + tid] = __expf(cum_lds[tid]);
    }
    __syncthreads();
    // ---- phase 2: Xw[p][s] = Xt[p][s] * w[s]  (vectorized)
    for (int seg = tid; seg < 64 * 16; seg += 256) {
        int pp = seg >> 4, sb = seg & 15;
        short8 v = *(const short8*)&Xt[pp * SP + sb * 8];
        short8 o;
        #pragma unroll
        for (int j = 0; j < 8; ++j)
            o[j] = (short)f2bf(bf2f((unsigned short)v[j]) * w_lds[sb * 8 + j]);
        *(short8*)&Xw[pp * SP + sb * 8] = o;
    }
    __syncthreads();
    int lane = tid & 63, wv = tid >> 6;
    int quad = lane >> 4, l15 = lane & 15;
    // ---- phase 3: T[p][n] = sum_s Xw[p][s] B[s][n]  (A=Xw, B-frag=Bt) -> TS
    {
        f32x4 acc[8] = {};
        for (int kk = 0; kk < 128; kk += 32) {
            short8 a = *(const short8*)&Xw[(16 * wv + l15) * SP + kk + quad * 8];
            #pragma unroll
            for (int jn = 0; jn < 8; ++jn) {
                short8 b = *(const short8*)&BtM[(16 * jn + l15) * SP + kk + quad * 8];
                acc[jn] = __builtin_amdgcn_mfma_f32_16x16x32_bf16(a, b, acc[jn], 0, 0, 0);
            }
        }
        size_t tsbase = (size_t)(bh * NCH + kch) * 8192;
        #pragma unroll
        for (int jn = 0; jn < 8; ++jn)
            #pragma unroll
            for (int r = 0; r < 4; ++r) {
                int pp = 16 * wv + quad * 4 + r, n = 16 * jn + l15;
                TS[tsbase + pp * 128 + n] = f2bf(acc[jn][r]);
            }
    }
    __syncthreads();  // Bt dead; M reuses BtM
    // ---- phase 4: G = C·B^T (both operands DIRECT FROM GLOBAL), decay -> M
    {
        f32x4 g[2][8] = {};
        for (int kk = 0; kk < 128; kk += 32) {
            int co = 2176 + kk + quad * 8;
            short8 a0 = *(const short8*)&xb[(size_t)(32 * wv + l15) * CONVD + co];
            short8 a1 = *(const short8*)&xb[(size_t)(32 * wv + 16 + l15) * CONVD + co];
            int bo = 2048 + kk + quad * 8;
            #pragma unroll
            for (int js = 0; js < 8; ++js) {
                short8 b = *(const short8*)&xb[(size_t)(16 * js + l15) * CONVD + bo];
                g[0][js] = __builtin_amdgcn_mfma_f32_16x16x32_bf16(a0, b, g[0][js], 0, 0, 0);
                g[1][js] = __builtin_amdgcn_mfma_f32_16x16x32_bf16(a1, b, g[1][js], 0, 0, 0);
            }
        }
        #pragma unroll
        for (int it = 0; it < 2; ++it)
            #pragma unroll
            for (int js = 0; js < 8; ++js) {
                int s = 16 * js + l15;
                float cs = cum_lds[s], ds = dt_lds[s];
                #pragma unroll
                for (int r = 0; r < 4; ++r) {
                    int t = 32 * wv + 16 * it + quad * 4 + r;
                    float f = (s <= t) ? __expf(cum_lds[t] - cs) * ds : 0.f;
                    BtM[t * SP + s] = f2bf(g[it][js][r] * f);
                }
            }
    }
    __syncthreads();
    // ---- phase 5: Y_intra = M @ X  (A=M from LDS, B-frag=Xt) -> ym
    {
        f32x4 y[2][4] = {};
        for (int kk = 0; kk < 128; kk += 32) {
            short8 a0 = *(const short8*)&BtM[(32 * wv + l15) * SP + kk + quad * 8];
            short8 a1 = *(const short8*)&BtM[(32 * wv + 16 + l15) * SP + kk + quad * 8];
            #pragma unroll
            for (int jp = 0; jp < 4; ++jp) {
                short8 b = *(const short8*)&Xt[(16 * jp + l15) * SP + kk + quad * 8];
                y[0][jp] = __builtin_amdgcn_mfma_f32_16x16x32_bf16(a0, b, y[0][jp], 0, 0, 0);
                y[1][jp] = __builtin_amdgcn_mfma_f32_16x16x32_bf16(a1, b, y[1][jp], 0, 0, 0);
            }
        }
        #pragma unroll
        for (int it = 0; it < 2; ++it)
            #pragma unroll
            for (int jp = 0; jp < 4; ++jp)
                #pragma unroll
                for (int r = 0; r < 4; ++r) {
                    int t = 32 * wv + 16 * it + quad * 4 + r;
                    int pp = 16 * jp + l15;
                    ym[(size_t)(tok0 + t) * DIN + h * 64 + pp] = f2bf(y[it][jp][r]);
                }
    }
}

// K2: state recurrence, in place on TS (read T_k, write S_before_k).
__global__ __launch_bounds__(128) void state_recur_kernel(
    unsigned short* __restrict__ TS, const float* __restrict__ abuf) {
    int bh = blockIdx.x >> 6, p = blockIdx.x & 63, n = threadIdx.x;
    float s = 0.f;
    for (int k = 0; k < NCH; ++k) {
        size_t base = ((size_t)(bh * NCH + k) * 64 + p) * 128 + n;
        float aT = abuf[(size_t)(bh * NCH + k) * 128 + 127];
        float tv = bf2f(TS[base]);
        TS[base] = f2bf(s);
        s = fmaf(aT, s, tv);
    }
}

// K3: Y += (a .* C) @ S_prev^T + D*x.  Fully LDS-free: a_t folded into A-frag
// (one scalar per lane), C from global, S from global (layout = B-frag shape).
__global__ __launch_bounds__(256) void chunk_inter_kernel(
    const unsigned short* __restrict__ xbc, const unsigned short* __restrict__ TS,
    const float* __restrict__ abuf, const float* __restrict__ Dp,
    unsigned short* ym) {
    __shared__ float a_ld[128];
    int tid = threadIdx.x;
    int kch = blockIdx.x, bh = blockIdx.y;
    int h = bh & 31, bi = bh >> 5;
    int tok0 = bi * SEQL + kch * CHT;
    if (tid < 128) a_ld[tid] = abuf[(size_t)(bh * NCH + kch) * 128 + tid];
    __syncthreads();
    int lane = tid & 63, wv = tid >> 6;
    int quad = lane >> 4, l15 = lane & 15;
    const unsigned short* xb = xbc + (size_t)tok0 * CONVD;
    size_t tsbase = (size_t)(bh * NCH + kch) * 8192;
    int t0 = 32 * wv + l15, t1 = t0 + 16;
    float at0 = a_ld[t0], at1 = a_ld[t1];
    f32x4 y[2][4] = {};
    for (int kk = 0; kk < 128; kk += 32) {
        int co = 2176 + kk + quad * 8;
        short8 c0 = *(const short8*)&xb[(size_t)t0 * CONVD + co];
        short8 c1 = *(const short8*)&xb[(size_t)t1 * CONVD + co];
        short8 a0, a1;
        #pragma unroll
        for (int j = 0; j < 8; ++j) {
            a0[j] = (short)f2bf(bf2f((unsigned short)c0[j]) * at0);
            a1[j] = (short)f2bf(bf2f((unsigned short)c1[j]) * at1);
        }
        #pragma unroll
        for (int jp = 0; jp < 4; ++jp) {
            short8 b = *(const short8*)&TS[tsbase + (size_t)(16 * jp + l15) * 128 + kk + quad * 8];
            y[0][jp] = __builtin_amdgcn_mfma_f32_16x16x32_bf16(a0, b, y[0][jp], 0, 0, 0);
            y[1][jp] = __builtin_amdgcn_mfma_f32_16x16x32_bf16(a1, b, y[1][jp], 0, 0, 0);
        }
    }
    float Dh = Dp[h];
    #pragma unroll
    for (int it = 0; it < 2; ++it)
        #pragma unroll
        for (int jp = 0; jp < 4; ++jp)
            #pragma unroll
            for (int r = 0; r < 4; ++r) {
                int t = 32 * wv + 16 * it + quad * 4 + r;
                int pp = 16 * jp + l15;
                size_t yi = (size_t)(tok0 + t) * DIN + h * 64 + pp;
                float xv = bf2f(xb[(size_t)t * CONVD + h * 64 + pp]);
                float yv = y[it][jp][r] + bf2f(ym[yi]) + Dh * xv;
                ym[yi] = f2bf(yv);
            }
}

// ---------------- gated rmsnorm ----------------
__global__ __launch_bounds__(256) void gated_norm_kernel(
    const unsigned short* __restrict__ y,
    const unsigned short* __restrict__ Z,
    const float* __restrict__ gw, unsigned short* mamba) {
    int tok = blockIdx.x, tid = threadIdx.x;
    float vals[8];
    float ss = 0;
    #pragma unroll
    for (int i = 0; i < 8; ++i) {
        int c = tid + i * 256;
        float yv = bf2f(y[(size_t)tok * DIN + c]);
        float zv = bf2f(Z[(size_t)tok * NBIG + c]);
        float g = yv * (zv / (1.0f + expf(-zv)));
        vals[i] = g;
        ss += g * g;
    }
    #pragma unroll
    for (int off = 32; off > 0; off >>= 1) ss += __shfl_xor(ss, off, 64);
    __shared__ float sred[4];
    if ((tid & 63) == 0) sred[tid >> 6] = ss;
    __syncthreads();
    float tot = sred[0] + sred[1] + sred[2] + sred[3];
    float r = rsqrtf(tot * (1.0f / DIN) + 1e-5f);
    #pragma unroll
    for (int i = 0; i < 8; ++i) {
        int c = tid + i * 256;
        mamba[(size_t)tok * DIN + c] = f2bf(vals[i] * r * gw[c]);
    }
}

// ---------------- chunked cumsum over L of Q (256 blocks) ----------------
__global__ void cumsum_pass1_kernel(const unsigned short* __restrict__ Z,
                                    float* __restrict__ S) {
    int cg = blockIdx.x & 3, ch = (blockIdx.x >> 2) & 31, bi = blockIdx.x >> 7;
    int c = cg * 256 + threadIdx.x;
    size_t base = (size_t)(bi * SEQL + ch * 128) * NBIG;
    float s = 0;
    for (int t = 0; t < 128; ++t)
        s += bf2f(Z[base + (size_t)t * NBIG + 5408 + c]);
    S[(bi * 32 + ch) * 1024 + c] = s;
}

__global__ void cumsum_pass2_kernel(unsigned short* __restrict__ Z,
                                    const float* __restrict__ S) {
    int cg = blockIdx.x & 3, ch = (blockIdx.x >> 2) & 31, bi = blockIdx.x >> 7;
    int c = cg * 256 + threadIdx.x;
    float run = 0;
    for (int k = 0; k < ch; ++k) run += S[(bi * 32 + k) * 1024 + c];
    size_t base = (size_t)(bi * SEQL + ch * 128) * NBIG;
    for (int t = 0; t < 128; ++t) {
        size_t row = base + (size_t)t * NBIG;
        run += bf2f(Z[row + 5408 + c]);
        ((float*)(Z + row))[c] = run;
    }
}

// ---------------- launch ----------------
extern "C" void kernel_launch(void* const* d_in, const int* in_sizes, int n_in,
                              void* d_out, int out_size, void* d_ws, size_t ws_size,
                              hipStream_t stream) {
    (void)in_sizes; (void)n_in; (void)out_size; (void)ws_size;
    const float* x        = (const float*)d_in[0];
    const float* norm_w   = (const float*)d_in[1];
    const float* in_projW = (const float*)d_in[2];
    const float* conv_W   = (const float*)d_in[3];
    const float* conv_b   = (const float*)d_in[4];
    const float* dt_bias  = (const float*)d_in[5];
    const float* A_log    = (const float*)d_in[6];
    const float* Dp       = (const float*)d_in[7];
    const float* gnorm_w  = (const float*)d_in[8];
    const float* zero_W   = (const float*)d_in[9];
    const float* one_W    = (const float*)d_in[10];
    const float* fusion_W = (const float*)d_in[11];
    float* out = (float*)d_out;

    char* p = (char*)d_ws;
    auto alloc = [&](size_t bytes) { char* r = p; p += (bytes + 255) & ~(size_t)255; return r; };
    unsigned short* Wf_t  = (unsigned short*)alloc((size_t)DMODEL * 6144 * 2);
    char* pool0 = p;
    unsigned short* xn_bf = (unsigned short*)alloc((size_t)NTOT * DMODEL * 2);
    unsigned short* zWb   = (unsigned short*)alloc((size_t)DMODEL * DIN * 2);
    unsigned short* oWb   = (unsigned short*)alloc((size_t)DMODEL * DIN * 2);
    unsigned short* Bt    = (unsigned short*)alloc((size_t)NBIG * DMODEL * 2);
    unsigned short* xbc   = (unsigned short*)pool0;  // alias over dead prep pool
    float* abuf = (float*)alloc((size_t)64 * NCH * 128 * 4);
    float* Sb   = (float*)alloc((size_t)2 * 32 * 1024 * 4);
    unsigned short* ym  = (unsigned short*)alloc((size_t)NTOT * DIN * 2);
    unsigned short* Zbf = (unsigned short*)alloc((size_t)NTOT * NBIG * 2);
    unsigned short* TS = (unsigned short*)d_out;  // 33.5MB exact fit; dead before final GEMM

    transpose_cast_kernel<<<dim3(DPROJ / 32, DMODEL / 32), dim3(32, 8), 0, stream>>>(
        in_projW, Bt, DMODEL, DPROJ);
    transpose_cast_kernel<<<dim3(DMODEL / 32, 6144 / 32), dim3(32, 8), 0, stream>>>(
        fusion_W, Wf_t, 6144, DMODEL);
    cast_bf16_kernel<<<2048, 256, 0, stream>>>(zero_W, zWb, DMODEL * DIN);
    cast_bf16_kernel<<<2048, 256, 0, stream>>>(one_W, oWb, DMODEL * DIN);
    zero_pad_kernel<<<384, 256, 0, stream>>>(
        Bt + (size_t)NREAL * DMODEL, (NBIG - NREAL) * DMODEL);

    rmsnorm_cast_kernel<<<NTOT, 256, 0, stream>>>(x, norm_w, xn_bf);

    gemm_bt_kernel<1><<<dim3(8, 8), 256, 0, stream>>>(
        Wf_t + 2048, 6144, zWb, DIN, Bt + (size_t)4384 * DMODEL, DMODEL, DIN,
        nullptr, nullptr);
    gemm_bt_kernel<1><<<dim3(8, 8), 256, 0, stream>>>(
        Wf_t + 4096, 6144, oWb, DIN, Bt + (size_t)5408 * DMODEL, DMODEL, DIN,
        nullptr, nullptr);

    gemm_bt_kernel<1><<<dim3(NBIG / 128, NTOT / 128), 256, 0, stream>>>(
        xn_bf, DMODEL, Bt, DMODEL, Zbf, NBIG, DMODEL, nullptr, nullptr);

    conv_silu_kernel<<<NTOT, 256, 0, stream>>>(Zbf, conv_W, conv_b, xbc);

    chunk_intra_kernel<<<dim3(NCH, 64), 256, 0, stream>>>(
        xbc, Zbf, dt_bias, A_log, TS, abuf, ym);
    state_recur_kernel<<<64 * 64, 128, 0, stream>>>(TS, abuf);
    chunk_inter_kernel<<<dim3(NCH, 64), 256, 0, stream>>>(
        xbc, TS, abuf, Dp, ym);

    gated_norm_kernel<<<NTOT, 256, 0, stream>>>(ym, Zbf, gnorm_w, ym);

    cumsum_pass1_kernel<<<256, 256, 0, stream>>>(Zbf, Sb);
    cumsum_pass2_kernel<<<256, 256, 0, stream>>>(Zbf, Sb);

    gemm_bt_kernel<2><<<dim3(DMODEL / 128, NTOT / 128), 256, 0, stream>>>(
        ym, DIN, Wf_t, 6144, out, DMODEL, DIN, x, Zbf);
}

// Round 5
// 670.957 us; speedup vs baseline: 3.4822x; 1.0986x over previous
//
#include <hip/hip_runtime.h>
#include <hip/hip_bf16.h>
#include <stdint.h>

// ---------------- problem constants ----------------
#define BATCH   2
#define SEQL    4096
#define DMODEL  1024
#define DIN     2048          // d_inner
#define NH      32
#define HDIM    64
#define DSTATE  128
#define CONVD   2304          // d_inner + 2*d_state
#define DPROJ   4384          // 2*d_inner + 2*d_state + nheads
#define NTOT    8192          // BATCH*SEQL
#define NBIG    6528          // padded: 4384 + 1024 + 1024 = 6432 -> 6528 (/128)
#define NREAL   6432
#define CHT     128           // SSD chunk length
#define NCH     32            // chunks per batch-sequence (4096/128)
#define SP      136           // padded LDS row stride for scan kernels
// Z (bf16) column layout: [0,2048)=z  [2048,4352)=xBC  [4352,4384)=dt
//   [4384,5408)=P (xn@Mzero)  [5408,6432)=Q (xn@Mone)
// After cumsum pass2: fp32 cumsum(Q) occupies bytes [0,4096) of each row.
//
// GEMM LDS xor-swizzle: logical element (row, c) of a 64-col K-panel is
// stored at halfword offset row*64 + ((c>>3 + row)&7)*8 + (c&7). The
// global_load_lds staging (dest forced = lane-contiguous) implements this
// by permuting the SOURCE chunk per lane; fragment reads apply the same
// swizzle -> 16 lanes/quad spread over all 8 bank groups (2-way = free)
// instead of 16-way conflicts on one group.

typedef __attribute__((ext_vector_type(8))) short short8;
typedef __attribute__((ext_vector_type(4))) float f32x4;

__device__ __forceinline__ unsigned short f2bf(float f) {
    unsigned int u = __builtin_bit_cast(unsigned int, f);
    return (unsigned short)((u + 0x7FFFu + ((u >> 16) & 1u)) >> 16);
}
__device__ __forceinline__ float bf2f(unsigned short u) {
    unsigned int v = ((unsigned int)u) << 16;
    return __builtin_bit_cast(float, v);
}

__device__ __forceinline__ void gload16(const void* g, void* l) {
    __builtin_amdgcn_global_load_lds(
        (const __attribute__((address_space(1))) unsigned int*)g,
        (__attribute__((address_space(3))) unsigned int*)l,
        16, 0, 0);
}

// ---------------- weight prep ----------------
__global__ void transpose_cast_kernel(const float* __restrict__ in,
                                      unsigned short* __restrict__ out,
                                      int R, int C) {
    __shared__ float tile[32][33];
    int c0 = blockIdx.x * 32, r0 = blockIdx.y * 32;
    int tx = threadIdx.x, ty = threadIdx.y;
    #pragma unroll
    for (int i = ty; i < 32; i += 8)
        tile[i][tx] = in[(size_t)(r0 + i) * C + c0 + tx];
    __syncthreads();
    #pragma unroll
    for (int i = ty; i < 32; i += 8)
        out[(size_t)(c0 + i) * R + r0 + tx] = f2bf(tile[tx][i]);
}

__global__ void cast_bf16_kernel(const float* __restrict__ in,
                                 unsigned short* __restrict__ out, int n4) {
    int i = (blockIdx.x * 256 + threadIdx.x) * 4;
    if (i < n4) {
        float4 v = *(const float4*)(in + i);
        ushort4 o;
        o.x = f2bf(v.x); o.y = f2bf(v.y); o.z = f2bf(v.z); o.w = f2bf(v.w);
        *(ushort4*)(out + i) = o;
    }
}

__global__ void zero_pad_kernel(unsigned short* __restrict__ p, int n) {
    int i = blockIdx.x * 256 + threadIdx.x;
    if (i < n) p[i] = 0;
}

// ---------------- rmsnorm + cast ----------------
__global__ __launch_bounds__(256) void rmsnorm_cast_kernel(
    const float* __restrict__ x, const float* __restrict__ w,
    unsigned short* __restrict__ xn) {
    int tok = blockIdx.x, tid = threadIdx.x;
    float4 v = ((const float4*)(x + (size_t)tok * DMODEL))[tid];
    float ss = v.x*v.x + v.y*v.y + v.z*v.z + v.w*v.w;
    #pragma unroll
    for (int off = 32; off > 0; off >>= 1) ss += __shfl_xor(ss, off, 64);
    __shared__ float sred[4];
    if ((tid & 63) == 0) sred[tid >> 6] = ss;
    __syncthreads();
    float tot = sred[0] + sred[1] + sred[2] + sred[3];
    float r = rsqrtf(tot * (1.0f / DMODEL) + 1e-5f);
    float4 wv = ((const float4*)w)[tid];
    ushort4 o;
    o.x = f2bf(v.x * r * wv.x); o.y = f2bf(v.y * r * wv.y);
    o.z = f2bf(v.z * r * wv.z); o.w = f2bf(v.w * r * wv.w);
    ((ushort4*)(xn + (size_t)tok * DMODEL))[tid] = o;
}

// ---------------- GEMM: C[M,N] = A[M,K] @ B[N,K]^T  (bf16 in, fp32 acc) ----
// MODE 1: bf16 out.  MODE 2: fp32 out = acc + x + P(bf16) + Qc(fp32).
// LDS xor-swizzled; block order remapped in bands of 8 bm-rows for L2 reuse
// (requires gridDim.y % 8 == 0).
template<int MODE>
__global__ __launch_bounds__(256) void gemm_bt_kernel(
    const unsigned short* __restrict__ A, int lda,
    const unsigned short* __restrict__ B, int ldb,
    void* __restrict__ Cout, int ldc, int K,
    const float* __restrict__ addX, const unsigned short* __restrict__ Zbuf) {
    __shared__ __align__(16) unsigned short sA[128 * 64];
    __shared__ __align__(16) unsigned short sB[128 * 64];
    int tid = threadIdx.x;
    // band-of-8 remap: consecutive blocks sweep all bn for 8 bm rows
    int bid = blockIdx.y * gridDim.x + blockIdx.x;
    int W = gridDim.x * 8;
    int band = bid / W, rem = bid % W;
    int bn = rem >> 3, bm = band * 8 + (rem & 7);
    int wave = tid >> 6, lane = tid & 63;
    int wm = wave >> 1, wn = wave & 1;
    f32x4 acc[4][4] = {};
    const unsigned short* Ab = A + (size_t)(bm * 128) * lda;
    const unsigned short* Bb = B + (size_t)(bn * 128) * ldb;
    int sRow = tid >> 3;
    int srcoff = (((tid & 7) - (tid >> 3)) & 7) * 8;  // swizzled source chunk
    int quad = lane >> 4, l15 = lane & 15;
    for (int k0 = 0; k0 < K; k0 += 64) {
        __syncthreads();
        #pragma unroll
        for (int it = 0; it < 4; ++it) {
            int row = sRow + it * 32;
            gload16(&Ab[(size_t)row * lda + k0 + srcoff], &sA[it * 2048 + tid * 8]);
            gload16(&Bb[(size_t)row * ldb + k0 + srcoff], &sB[it * 2048 + tid * 8]);
        }
        __syncthreads();
        #pragma unroll
        for (int kk = 0; kk < 64; kk += 32) {
            short8 a[4], b[4];
            #pragma unroll
            for (int i = 0; i < 4; ++i) {
                int mr = wm * 64 + i * 16 + l15;
                a[i] = *(const short8*)&sA[mr * 64 + (((kk >> 3) + quad + mr) & 7) * 8];
                int nr = wn * 64 + i * 16 + l15;
                b[i] = *(const short8*)&sB[nr * 64 + (((kk >> 3) + quad + nr) & 7) * 8];
            }
            #pragma unroll
            for (int i = 0; i < 4; ++i)
                #pragma unroll
                for (int j = 0; j < 4; ++j)
                    acc[i][j] = __builtin_amdgcn_mfma_f32_16x16x32_bf16(
                        a[i], b[j], acc[i][j], 0, 0, 0);
        }
    }
    int rbase = bm * 128 + wm * 64 + quad * 4;
    int cbase = bn * 128 + wn * 64 + l15;
    #pragma unroll
    for (int i = 0; i < 4; ++i) {
        #pragma unroll
        for (int r = 0; r < 4; ++r) {
            int gr = rbase + i * 16 + r;
            if constexpr (MODE == 1) {
                unsigned short* crow = (unsigned short*)Cout + (size_t)gr * ldc + cbase;
                #pragma unroll
                for (int j = 0; j < 4; ++j) crow[j * 16] = f2bf(acc[i][j][r]);
            } else {
                float* crow = (float*)Cout + (size_t)gr * ldc + cbase;
                const float* xr = addX + (size_t)gr * DMODEL + cbase;
                const unsigned short* zrow = Zbuf + (size_t)gr * NBIG;
                const float* qrow = (const float*)zrow;
                #pragma unroll
                for (int j = 0; j < 4; ++j)
                    crow[j * 16] = acc[i][j][r] + xr[j * 16]
                                 + bf2f(zrow[4384 + cbase + j * 16])
                                 + qrow[cbase + j * 16];
            }
        }
    }
}

// ---- 64x64-tile GEMM (bf16 out) for the small prep GEMMs: 4x occupancy ----
__global__ __launch_bounds__(256) void gemm64_kernel(
    const unsigned short* __restrict__ A, int lda,
    const unsigned short* __restrict__ B, int ldb,
    unsigned short* __restrict__ Cout, int ldc, int K) {
    __shared__ __align__(16) unsigned short sA[64 * 64];
    __shared__ __align__(16) unsigned short sB[64 * 64];
    int tid = threadIdx.x;
    int bn = blockIdx.x, bm = blockIdx.y;
    int wave = tid >> 6, lane = tid & 63;
    int wm = wave >> 1, wn = wave & 1;
    f32x4 acc[2][2] = {};
    const unsigned short* Ab = A + (size_t)(bm * 64) * lda;
    const unsigned short* Bb = B + (size_t)(bn * 64) * ldb;
    int sRow = tid >> 3;
    int srcoff = (((tid & 7) - (tid >> 3)) & 7) * 8;
    int quad = lane >> 4, l15 = lane & 15;
    for (int k0 = 0; k0 < K; k0 += 64) {
        __syncthreads();
        #pragma unroll
        for (int it = 0; it < 2; ++it) {
            int row = sRow + it * 32;
            gload16(&Ab[(size_t)row * lda + k0 + srcoff], &sA[it * 2048 + tid * 8]);
            gload16(&Bb[(size_t)row * ldb + k0 + srcoff], &sB[it * 2048 + tid * 8]);
        }
        __syncthreads();
        #pragma unroll
        for (int kk = 0; kk < 64; kk += 32) {
            short8 a[2], b[2];
            #pragma unroll
            for (int i = 0; i < 2; ++i) {
                int mr = wm * 32 + i * 16 + l15;
                a[i] = *(const short8*)&sA[mr * 64 + (((kk >> 3) + quad + mr) & 7) * 8];
                int nr = wn * 32 + i * 16 + l15;
                b[i] = *(const short8*)&sB[nr * 64 + (((kk >> 3) + quad + nr) & 7) * 8];
            }
            #pragma unroll
            for (int i = 0; i < 2; ++i)
                #pragma unroll
                for (int j = 0; j < 2; ++j)
                    acc[i][j] = __builtin_amdgcn_mfma_f32_16x16x32_bf16(
                        a[i], b[j], acc[i][j], 0, 0, 0);
        }
    }
    int rbase = bm * 64 + wm * 32 + quad * 4;
    int cbase = bn * 64 + wn * 32 + l15;
    #pragma unroll
    for (int i = 0; i < 2; ++i)
        #pragma unroll
        for (int r = 0; r < 4; ++r) {
            int gr = rbase + i * 16 + r;
            unsigned short* crow = Cout + (size_t)gr * ldc + cbase;
            #pragma unroll
            for (int j = 0; j < 2; ++j) crow[j * 16] = f2bf(acc[i][j][r]);
        }
}

// ---------------- conv4 (causal, depthwise) + silu ----------------
__global__ __launch_bounds__(256) void conv_silu_kernel(
    const unsigned short* __restrict__ Z, const float* __restrict__ convW,
    const float* __restrict__ convB, unsigned short* __restrict__ xbc) {
    int tok = blockIdx.x;
    int bi = tok >> 12, t = tok & 4095;
    for (int c = threadIdx.x; c < CONVD; c += 256) {
        float acc = convB[c];
        #pragma unroll
        for (int k = 0; k < 4; ++k) {
            int tt = t - 3 + k;
            if (tt >= 0)
                acc += bf2f(Z[(size_t)(bi * SEQL + tt) * NBIG + 2048 + c]) * convW[k * CONVD + c];
        }
        xbc[(size_t)tok * CONVD + c] = f2bf(acc / (1.0f + expf(-acc)));
    }
}

// ================= SSD chunked scan =================
__global__ __launch_bounds__(256, 2) void chunk_intra_kernel(
    const unsigned short* __restrict__ xbc, const unsigned short* __restrict__ Z,
    const float* __restrict__ dt_bias, const float* __restrict__ A_log,
    unsigned short* __restrict__ TS, float* __restrict__ abuf,
    unsigned short* __restrict__ ym) {
    __shared__ __align__(16) unsigned short Xt[64 * SP];
    __shared__ __align__(16) unsigned short Xw[64 * SP];
    __shared__ __align__(16) unsigned short BtM[128 * SP];
    __shared__ float dt_lds[128], dtA_lds[128], cum_lds[128], w_lds[128];
    int tid = threadIdx.x;
    int kch = blockIdx.x, bh = blockIdx.y;
    int h = bh & 31, bi = bh >> 5;
    int tok0 = bi * SEQL + kch * CHT;
    const unsigned short* xb = xbc + (size_t)tok0 * CONVD;
    if (tid < 128) {
        float v = bf2f(Z[(size_t)(tok0 + tid) * NBIG + 4352 + h]) + dt_bias[h];
        float sp = (v > 20.f) ? v : log1pf(expf(v));
        dt_lds[tid] = sp;
        dtA_lds[tid] = -sp * expf(A_log[h]);
    }
    for (int seg = tid; seg < 128 * 16; seg += 256) {
        int s = seg & 127, nb = seg >> 7;
        short8 v = *(const short8*)&xb[(size_t)s * CONVD + 2048 + nb * 8];
        #pragma unroll
        for (int j = 0; j < 8; ++j) BtM[(nb * 8 + j) * SP + s] = (unsigned short)v[j];
    }
    for (int seg = tid; seg < 128 * 8; seg += 256) {
        int s = seg & 127, pb = seg >> 7;
        short8 v = *(const short8*)&xb[(size_t)s * CONVD + h * 64 + pb * 8];
        #pragma unroll
        for (int j = 0; j < 8; ++j) Xt[(pb * 8 + j) * SP + s] = (unsigned short)v[j];
    }
    __syncthreads();
    if (tid < 128) {
        int lw = tid & 63;
        float v = dtA_lds[tid];
        #pragma unroll
        for (int off = 1; off < 64; off <<= 1) {
            float o = __shfl_up(v, off, 64);
            if (lw >= off) v += o;
        }
        cum_lds[tid] = v;
    }
    __syncthreads();
    if (tid >= 64 && tid < 128) cum_lds[tid] += cum_lds[63];
    __syncthreads();
    if (tid < 128) {
        float cT = cum_lds[127];
        w_lds[tid] = __expf(cT - cum_lds[tid]) * dt_lds[tid];
        abuf[(size_t)(bh * NCH + kch) * 128 + tid] = __expf(cum_lds[tid]);
    }
    __syncthreads();
    for (int seg = tid; seg < 64 * 16; seg += 256) {
        int pp = seg >> 4, sb = seg & 15;
        short8 v = *(const short8*)&Xt[pp * SP + sb * 8];
        short8 o;
        #pragma unroll
        for (int j = 0; j < 8; ++j)
            o[j] = (short)f2bf(bf2f((unsigned short)v[j]) * w_lds[sb * 8 + j]);
        *(short8*)&Xw[pp * SP + sb * 8] = o;
    }
    __syncthreads();
    int lane = tid & 63, wv = tid >> 6;
    int quad = lane >> 4, l15 = lane & 15;
    {
        f32x4 acc[8] = {};
        for (int kk = 0; kk < 128; kk += 32) {
            short8 a = *(const short8*)&Xw[(16 * wv + l15) * SP + kk + quad * 8];
            #pragma unroll
            for (int jn = 0; jn < 8; ++jn) {
                short8 b = *(const short8*)&BtM[(16 * jn + l15) * SP + kk + quad * 8];
                acc[jn] = __builtin_amdgcn_mfma_f32_16x16x32_bf16(a, b, acc[jn], 0, 0, 0);
            }
        }
        size_t tsbase = (size_t)(bh * NCH + kch) * 8192;
        #pragma unroll
        for (int jn = 0; jn < 8; ++jn)
            #pragma unroll
            for (int r = 0; r < 4; ++r) {
                int pp = 16 * wv + quad * 4 + r, n = 16 * jn + l15;
                TS[tsbase + pp * 128 + n] = f2bf(acc[jn][r]);
            }
    }
    __syncthreads();
    {
        f32x4 g[2][8] = {};
        for (int kk = 0; kk < 128; kk += 32) {
            int co = 2176 + kk + quad * 8;
            short8 a0 = *(const short8*)&xb[(size_t)(32 * wv + l15) * CONVD + co];
            short8 a1 = *(const short8*)&xb[(size_t)(32 * wv + 16 + l15) * CONVD + co];
            int bo = 2048 + kk + quad * 8;
            #pragma unroll
            for (int js = 0; js < 8; ++js) {
                short8 b = *(const short8*)&xb[(size_t)(16 * js + l15) * CONVD + bo];
                g[0][js] = __builtin_amdgcn_mfma_f32_16x16x32_bf16(a0, b, g[0][js], 0, 0, 0);
                g[1][js] = __builtin_amdgcn_mfma_f32_16x16x32_bf16(a1, b, g[1][js], 0, 0, 0);
            }
        }
        #pragma unroll
        for (int it = 0; it < 2; ++it)
            #pragma unroll
            for (int js = 0; js < 8; ++js) {
                int s = 16 * js + l15;
                float cs = cum_lds[s], ds = dt_lds[s];
                #pragma unroll
                for (int r = 0; r < 4; ++r) {
                    int t = 32 * wv + 16 * it + quad * 4 + r;
                    float f = (s <= t) ? __expf(cum_lds[t] - cs) * ds : 0.f;
                    BtM[t * SP + s] = f2bf(g[it][js][r] * f);
                }
            }
    }
    __syncthreads();
    {
        f32x4 y[2][4] = {};
        for (int kk = 0; kk < 128; kk += 32) {
            short8 a0 = *(const short8*)&BtM[(32 * wv + l15) * SP + kk + quad * 8];
            short8 a1 = *(const short8*)&BtM[(32 * wv + 16 + l15) * SP + kk + quad * 8];
            #pragma unroll
            for (int jp = 0; jp < 4; ++jp) {
                short8 b = *(const short8*)&Xt[(16 * jp + l15) * SP + kk + quad * 8];
                y[0][jp] = __builtin_amdgcn_mfma_f32_16x16x32_bf16(a0, b, y[0][jp], 0, 0, 0);
                y[1][jp] = __builtin_amdgcn_mfma_f32_16x16x32_bf16(a1, b, y[1][jp], 0, 0, 0);
            }
        }
        #pragma unroll
        for (int it = 0; it < 2; ++it)
            #pragma unroll
            for (int jp = 0; jp < 4; ++jp)
                #pragma unroll
                for (int r = 0; r < 4; ++r) {
                    int t = 32 * wv + 16 * it + quad * 4 + r;
                    int pp = 16 * jp + l15;
                    ym[(size_t)(tok0 + t) * DIN + h * 64 + pp] = f2bf(y[it][jp][r]);
                }
    }
}

__global__ __launch_bounds__(128) void state_recur_kernel(
    unsigned short* __restrict__ TS, const float* __restrict__ abuf) {
    int bh = blockIdx.x >> 6, p = blockIdx.x & 63, n = threadIdx.x;
    float s = 0.f;
    for (int k = 0; k < NCH; ++k) {
        size_t base = ((size_t)(bh * NCH + k) * 64 + p) * 128 + n;
        float aT = abuf[(size_t)(bh * NCH + k) * 128 + 127];
        float tv = bf2f(TS[base]);
        TS[base] = f2bf(s);
        s = fmaf(aT, s, tv);
    }
}

__global__ __launch_bounds__(256) void chunk_inter_kernel(
    const unsigned short* __restrict__ xbc, const unsigned short* __restrict__ TS,
    const float* __restrict__ abuf, const float* __restrict__ Dp,
    unsigned short* ym) {
    __shared__ float a_ld[128];
    int tid = threadIdx.x;
    int kch = blockIdx.x, bh = blockIdx.y;
    int h = bh & 31, bi = bh >> 5;
    int tok0 = bi * SEQL + kch * CHT;
    if (tid < 128) a_ld[tid] = abuf[(size_t)(bh * NCH + kch) * 128 + tid];
    __syncthreads();
    int lane = tid & 63, wv = tid >> 6;
    int quad = lane >> 4, l15 = lane & 15;
    const unsigned short* xb = xbc + (size_t)tok0 * CONVD;
    size_t tsbase = (size_t)(bh * NCH + kch) * 8192;
    int t0 = 32 * wv + l15, t1 = t0 + 16;
    float at0 = a_ld[t0], at1 = a_ld[t1];
    f32x4 y[2][4] = {};
    for (int kk = 0; kk < 128; kk += 32) {
        int co = 2176 + kk + quad * 8;
        short8 c0 = *(const short8*)&xb[(size_t)t0 * CONVD + co];
        short8 c1 = *(const short8*)&xb[(size_t)t1 * CONVD + co];
        short8 a0, a1;
        #pragma unroll
        for (int j = 0; j < 8; ++j) {
            a0[j] = (short)f2bf(bf2f((unsigned short)c0[j]) * at0);
            a1[j] = (short)f2bf(bf2f((unsigned short)c1[j]) * at1);
        }
        #pragma unroll
        for (int jp = 0; jp < 4; ++jp) {
            short8 b = *(const short8*)&TS[tsbase + (size_t)(16 * jp + l15) * 128 + kk + quad * 8];
            y[0][jp] = __builtin_amdgcn_mfma_f32_16x16x32_bf16(a0, b, y[0][jp], 0, 0, 0);
            y[1][jp] = __builtin_amdgcn_mfma_f32_16x16x32_bf16(a1, b, y[1][jp], 0, 0, 0);
        }
    }
    float Dh = Dp[h];
    #pragma unroll
    for (int it = 0; it < 2; ++it)
        #pragma unroll
        for (int jp = 0; jp < 4; ++jp)
            #pragma unroll
            for (int r = 0; r < 4; ++r) {
                int t = 32 * wv + 16 * it + quad * 4 + r;
                int pp = 16 * jp + l15;
                size_t yi = (size_t)(tok0 + t) * DIN + h * 64 + pp;
                float xv = bf2f(xb[(size_t)t * CONVD + h * 64 + pp]);
                float yv = y[it][jp][r] + bf2f(ym[yi]) + Dh * xv;
                ym[yi] = f2bf(yv);
            }
}

// ---------------- gated rmsnorm ----------------
__global__ __launch_bounds__(256) void gated_norm_kernel(
    const unsigned short* __restrict__ y,
    const unsigned short* __restrict__ Z,
    const float* __restrict__ gw, unsigned short* mamba) {
    int tok = blockIdx.x, tid = threadIdx.x;
    float vals[8];
    float ss = 0;
    #pragma unroll
    for (int i = 0; i < 8; ++i) {
        int c = tid + i * 256;
        float yv = bf2f(y[(size_t)tok * DIN + c]);
        float zv = bf2f(Z[(size_t)tok * NBIG + c]);
        float g = yv * (zv / (1.0f + expf(-zv)));
        vals[i] = g;
        ss += g * g;
    }
    #pragma unroll
    for (int off = 32; off > 0; off >>= 1) ss += __shfl_xor(ss, off, 64);
    __shared__ float sred[4];
    if ((tid & 63) == 0) sred[tid >> 6] = ss;
    __syncthreads();
    float tot = sred[0] + sred[1] + sred[2] + sred[3];
    float r = rsqrtf(tot * (1.0f / DIN) + 1e-5f);
    #pragma unroll
    for (int i = 0; i < 8; ++i) {
        int c = tid + i * 256;
        mamba[(size_t)tok * DIN + c] = f2bf(vals[i] * r * gw[c]);
    }
}

// ---------------- chunked cumsum over L of Q ----------------
__global__ void cumsum_pass1_kernel(const unsigned short* __restrict__ Z,
                                    float* __restrict__ S) {
    int cg = blockIdx.x & 3, ch = (blockIdx.x >> 2) & 31, bi = blockIdx.x >> 7;
    int c = cg * 256 + threadIdx.x;
    size_t base = (size_t)(bi * SEQL + ch * 128) * NBIG;
    float s = 0;
    for (int t = 0; t < 128; ++t)
        s += bf2f(Z[base + (size_t)t * NBIG + 5408 + c]);
    S[(bi * 32 + ch) * 1024 + c] = s;
}

__global__ void cumsum_pass2_kernel(unsigned short* __restrict__ Z,
                                    const float* __restrict__ S) {
    int cg = blockIdx.x & 3, ch = (blockIdx.x >> 2) & 31, bi = blockIdx.x >> 7;
    int c = cg * 256 + threadIdx.x;
    float run = 0;
    for (int k = 0; k < ch; ++k) run += S[(bi * 32 + k) * 1024 + c];
    size_t base = (size_t)(bi * SEQL + ch * 128) * NBIG;
    for (int t = 0; t < 128; ++t) {
        size_t row = base + (size_t)t * NBIG;
        run += bf2f(Z[row + 5408 + c]);
        ((float*)(Z + row))[c] = run;
    }
}

// ---------------- launch ----------------
extern "C" void kernel_launch(void* const* d_in, const int* in_sizes, int n_in,
                              void* d_out, int out_size, void* d_ws, size_t ws_size,
                              hipStream_t stream) {
    (void)in_sizes; (void)n_in; (void)out_size; (void)ws_size;
    const float* x        = (const float*)d_in[0];
    const float* norm_w   = (const float*)d_in[1];
    const float* in_projW = (const float*)d_in[2];
    const float* conv_W   = (const float*)d_in[3];
    const float* conv_b   = (const float*)d_in[4];
    const float* dt_bias  = (const float*)d_in[5];
    const float* A_log    = (const float*)d_in[6];
    const float* Dp       = (const float*)d_in[7];
    const float* gnorm_w  = (const float*)d_in[8];
    const float* zero_W   = (const float*)d_in[9];
    const float* one_W    = (const float*)d_in[10];
    const float* fusion_W = (const float*)d_in[11];
    float* out = (float*)d_out;

    char* p = (char*)d_ws;
    auto alloc = [&](size_t bytes) { char* r = p; p += (bytes + 255) & ~(size_t)255; return r; };
    unsigned short* Wf_t  = (unsigned short*)alloc((size_t)DMODEL * 6144 * 2);
    char* pool0 = p;
    unsigned short* xn_bf = (unsigned short*)alloc((size_t)NTOT * DMODEL * 2);
    unsigned short* zWb   = (unsigned short*)alloc((size_t)DMODEL * DIN * 2);
    unsigned short* oWb   = (unsigned short*)alloc((size_t)DMODEL * DIN * 2);
    unsigned short* Bt    = (unsigned short*)alloc((size_t)NBIG * DMODEL * 2);
    unsigned short* xbc   = (unsigned short*)pool0;  // alias over dead prep pool
    float* abuf = (float*)alloc((size_t)64 * NCH * 128 * 4);
    float* Sb   = (float*)alloc((size_t)2 * 32 * 1024 * 4);
    unsigned short* ym  = (unsigned short*)alloc((size_t)NTOT * DIN * 2);
    unsigned short* Zbf = (unsigned short*)alloc((size_t)NTOT * NBIG * 2);
    unsigned short* TS = (unsigned short*)d_out;  // 33.5MB exact fit; dead before final GEMM

    transpose_cast_kernel<<<dim3(DPROJ / 32, DMODEL / 32), dim3(32, 8), 0, stream>>>(
        in_projW, Bt, DMODEL, DPROJ);
    transpose_cast_kernel<<<dim3(DMODEL / 32, 6144 / 32), dim3(32, 8), 0, stream>>>(
        fusion_W, Wf_t, 6144, DMODEL);
    cast_bf16_kernel<<<2048, 256, 0, stream>>>(zero_W, zWb, DMODEL * DIN);
    cast_bf16_kernel<<<2048, 256, 0, stream>>>(one_W, oWb, DMODEL * DIN);
    zero_pad_kernel<<<384, 256, 0, stream>>>(
        Bt + (size_t)NREAL * DMODEL, (NBIG - NREAL) * DMODEL);

    rmsnorm_cast_kernel<<<NTOT, 256, 0, stream>>>(x, norm_w, xn_bf);

    // Mzero^T, Mone^T into Bt rows [4384,6432)  (64-tile: 256 blocks each)
    gemm64_kernel<<<dim3(16, 16), 256, 0, stream>>>(
        Wf_t + 2048, 6144, zWb, DIN, Bt + (size_t)4384 * DMODEL, DMODEL, DIN);
    gemm64_kernel<<<dim3(16, 16), 256, 0, stream>>>(
        Wf_t + 4096, 6144, oWb, DIN, Bt + (size_t)5408 * DMODEL, DMODEL, DIN);

    gemm_bt_kernel<1><<<dim3(NBIG / 128, NTOT / 128), 256, 0, stream>>>(
        xn_bf, DMODEL, Bt, DMODEL, Zbf, NBIG, DMODEL, nullptr, nullptr);

    conv_silu_kernel<<<NTOT, 256, 0, stream>>>(Zbf, conv_W, conv_b, xbc);

    chunk_intra_kernel<<<dim3(NCH, 64), 256, 0, stream>>>(
        xbc, Zbf, dt_bias, A_log, TS, abuf, ym);
    state_recur_kernel<<<64 * 64, 128, 0, stream>>>(TS, abuf);
    chunk_inter_kernel<<<dim3(NCH, 64), 256, 0, stream>>>(
        xbc, TS, abuf, Dp, ym);

    gated_norm_kernel<<<NTOT, 256, 0, stream>>>(ym, Zbf, gnorm_w, ym);

    cumsum_pass1_kernel<<<256, 256, 0, stream>>>(Zbf, Sb);
    cumsum_pass2_kernel<<<256, 256, 0, stream>>>(Zbf, Sb);

    gemm_bt_kernel<2><<<dim3(DMODEL / 128, NTOT / 128), 256, 0, stream>>>(
        ym, DIN, Wf_t, 6144, out, DMODEL, DIN, x, Zbf);
}